// Round 4
// baseline (11005.479 us; speedup 1.0000x reference)
//
#include <hip/hip_runtime.h>
#include <hip/hip_bf16.h>

#define Bz 4
#define Cc 64
#define Tt 1000
#define Ff 129
#define TF 129000            // Tt*Ff
#define CTF 8256000          // Cc*TF
#define SZ 33024000L         // Bz*CTF
#define EPSv 1e-5f

#define KQK 544              // 516 padded to mult of 32
#define KPV 1024             // 1000 padded
#define LDP 2000             // P row stride in bf16 (= 1000 f32 reused in place)
#define NV 2064              // 16*129

typedef __attribute__((ext_vector_type(8))) short bf16x8;
typedef __attribute__((ext_vector_type(4))) float f32x4;

// bf16 <-> bits helpers (no .data member on this ROCm's __hip_bfloat16)
__device__ __forceinline__ ushort bf_bits(__hip_bfloat16 h){
  union { __hip_bfloat16 h; ushort u; } c; c.h = h; return c.u;
}
__device__ __forceinline__ float bits_f32(ushort u){
  union { float f; unsigned int i; } c; c.i = ((unsigned int)u) << 16; return c.f;
}

// ---------------- reduction helpers ----------------
__device__ __forceinline__ float wave_sum(float v){
#pragma unroll
  for (int o = 32; o; o >>= 1) v += __shfl_down(v, o, 64);
  return v;
}
__device__ __forceinline__ float wave_bcast_sum(float v){
#pragma unroll
  for (int o = 1; o < 64; o <<= 1) v += __shfl_xor(v, o, 64);
  return v;
}
__device__ __forceinline__ float blk_sum256(float v, float* red){
  __syncthreads();
  v = wave_sum(v);
  int tid = threadIdx.x;
  if ((tid & 63) == 0) red[tid >> 6] = v;
  __syncthreads();
  return red[0] + red[1] + red[2] + red[3];
}
__device__ __forceinline__ float blk_max256(float v, float* red){
  __syncthreads();
#pragma unroll
  for (int o = 32; o; o >>= 1) v = fmaxf(v, __shfl_down(v, o, 64));
  int tid = threadIdx.x;
  if ((tid & 63) == 0) red[tid >> 6] = v;
  __syncthreads();
  return fmaxf(fmaxf(red[0], red[1]), fmaxf(red[2], red[3]));
}

// ---------------- misc ----------------
// zero stat[8] + chm[6*256] once at start (each ln4d stage owns one chm section)
__global__ void k_zeroinit(float* stat, float* chm){
  int i = blockIdx.x*256 + threadIdx.x;
  if (i < 8) stat[i] = 0.f;
  if (i < 1536) chm[i] = 0.f;
}
// zero pstat[8000] (aliases gapv; must run AFTER the lisa loop, before k_projA)
__global__ void k_zerop(float* ps){
  int i = blockIdx.x*256 + threadIdx.x;
  if (i < 8000) ps[i] = 0.f;
}

// ln4d: LN over channel axis per (b,t,f); std = sqrt(max(var, EPS))
// Fused per-(b,c) channel-SUM accumulation (replaces the k_chmean re-read pass):
// fast path = full wave, single b -> 64 wave_sums + 64 atomics per wave.
// chm section must be zeroed beforehand; holds SUM (k_filt applies 1/TF).
__global__ __launch_bounds__(256) void k_ln4d(const float* __restrict__ in, float* __restrict__ out,
                       const float* __restrict__ g, const float* __restrict__ be,
                       float* __restrict__ chm){
  int gid = blockIdx.x*256 + threadIdx.x;
  bool valid = gid < Bz*TF;
  int b = 0;
  float v[64];
  if (valid){
    b = gid / TF;
    int p = gid - b*TF;
    size_t base = (size_t)b*CTF + p;
    float s1 = 0.f, s2 = 0.f;
#pragma unroll
    for (int c = 0; c < 64; c++){ float x = in[base + (size_t)c*TF]; v[c] = x; s1 += x; s2 += x*x; }
    float mu = s1*(1.f/64.f);
    float var = s2*(1.f/64.f) - mu*mu;
    float rstd = rsqrtf(fmaxf(var, EPSv));
#pragma unroll
    for (int c = 0; c < 64; c++){
      float o = (v[c]-mu)*rstd*g[c] + be[c];
      v[c] = o;
      out[base + (size_t)c*TF] = o;
    }
  } else {
#pragma unroll
    for (int c = 0; c < 64; c++) v[c] = 0.f;
  }
  unsigned long long bal = __ballot(valid);
  int blo = __shfl(b, 0, 64), bhi = __shfl(b, 63, 64);
  if (bal == ~0ull && blo == bhi){
#pragma unroll
    for (int c = 0; c < 64; c++){
      float s = wave_sum(v[c]);
      if ((threadIdx.x & 63) == 0) atomicAdd(&chm[blo*64 + c], s);
    }
  } else if (valid){
    // boundary waves (b transition or grid tail): ~4 of 8064 waves
    for (int c = 0; c < 64; c++) atomicAdd(&chm[b*64 + c], v[c]);
  }
}

// filt from channel SUMS (1/TF folded in before tanh; linear so exact)
__global__ void k_filt(const float* __restrict__ m, const float* __restrict__ w, float* __restrict__ filt){
  int t = threadIdx.x;
  if (t >= Bz*12) return;
  int b = t/12, gk = t - b*12;
  float s = 0.f;
  for (int c = 0; c < 64; c++) s += m[b*64+c]*w[gk*64+c];
  filt[t] = tanhf(s * (1.f/(float)TF));
}

// lisa horizontal: one wave per (b,c,t) row of 129
__global__ void k_lisa_h(const float* __restrict__ in, float* __restrict__ out,
                         const float* __restrict__ filt, const float* __restrict__ iap,
                         const float* __restrict__ llp, const float* __restrict__ lhp, int dil){
  __shared__ float r[132];
  int row = blockIdx.x;
  int c = (row / Tt) % Cc;
  int b = row / (Tt*Cc);
  size_t base = (size_t)row * Ff;
  int lane = threadIdx.x;
  float s = 0.f;
  for (int f = lane; f < Ff; f += 64){ float x = in[base+f]; r[f] = x; s += x; }
  s = wave_bcast_sum(s);
  float gap = s * (1.f/129.f);
  __syncthreads();
  int g3 = b*12 + (c>>4)*3;
  float w0 = filt[g3], w1 = filt[g3+1], w2 = filt[g3+2];
  float ia = iap[c], ll = llp[c], lh1 = lhp[c] + 1.f, ia1 = ia + 1.f;
  for (int f = lane; f < Ff; f += 64){
    int fm = f - dil; fm = fm < 0 ? -fm : fm;
    int fp = f + dil; fp = fp > 128 ? 256 - fp : fp;
    float conv = w0*r[fm] + w1*r[f] + w2*r[fp];
    out[base+f] = (conv*ia1 - ia*gap)*ll + r[f]*lh1;
  }
}

// column means over t per (b,c,f)
__global__ void k_colmean(const float* __restrict__ in, float* __restrict__ gapv){
  int lane = threadIdx.x & 63, strip = threadIdx.x >> 6;
  int f = blockIdx.x*64 + lane;
  int c = blockIdx.y, b = blockIdx.z;
  size_t cb = ((size_t)(b*Cc + c))*TF + f;
  float s = 0.f;
  if (f < Ff){ for (int t = strip; t < Tt; t += 4) s += in[cb + (size_t)t*Ff]; }
  __shared__ float sm[256];
  sm[threadIdx.x] = s; __syncthreads();
  if (strip == 0 && f < Ff){
    float tot = sm[threadIdx.x] + sm[threadIdx.x+64] + sm[threadIdx.x+128] + sm[threadIdx.x+192];
    gapv[(b*Cc + c)*Ff + f] = tot * (1.f/(float)Tt);
  }
}

// lisa vertical fused with bsum accumulate
__global__ void k_lisa_v(const float* __restrict__ in, const float* __restrict__ x,
                         float* __restrict__ A, const float* __restrict__ filt,
                         const float* __restrict__ gapv,
                         const float* __restrict__ iap, const float* __restrict__ llp,
                         const float* __restrict__ lhp,
                         const float* __restrict__ mgp, const float* __restrict__ mbp,
                         int dil, int accum){
  int lane = threadIdx.x & 63, strip = threadIdx.x >> 6;
  int ftile = blockIdx.x % 3, tch = blockIdx.x / 3;
  int f = ftile*64 + lane;
  if (f >= Ff) return;
  int c = blockIdx.y, b = blockIdx.z;
  int g3 = b*12 + (c>>4)*3;
  float w0 = filt[g3], w1 = filt[g3+1], w2 = filt[g3+2];
  float ia = iap[c], ll = llp[c], lh1 = lhp[c]+1.f, ia1 = ia+1.f;
  float mg = mgp[c], mb = mbp[c];
  float gap = gapv[(b*Cc+c)*Ff + f];
  size_t cb = ((size_t)(b*Cc + c))*TF + f;
  int tend = tch*100 + 100;
  for (int t = tch*100 + strip; t < tend; t += 4){
    int tm = t - dil; tm = tm < 0 ? -tm : tm;
    int tp = t + dil; tp = tp > 999 ? 1998 - tp : tp;
    float vm = in[cb + (size_t)tm*Ff];
    float vc = in[cb + (size_t)t*Ff];
    float vp = in[cb + (size_t)tp*Ff];
    float conv = w0*vm + w1*vc + w2*vp;
    float val = (conv*ia1 - ia*gap)*ll + vc*lh1;
    float o = mg*val + mb*x[cb + (size_t)t*Ff];
    size_t oi = cb + (size_t)t*Ff;
    A[oi] = accum ? (A[oi] + o) : o;
  }
}

// 1x1 conv 64->64, fused with per-batch global stats (sum, sumsq) for the
// following GroupNorm. stat must be zeroed before this launch.
// Weights read directly from global with wave-uniform addresses (scalar-load path).
__global__ __launch_bounds__(256) void k_convb(const float* __restrict__ in, float* __restrict__ out,
                        const float* __restrict__ W, const float* __restrict__ bias,
                        float* __restrict__ stat){
  __shared__ float bacc[8];
  if (threadIdx.x < 8) bacc[threadIdx.x] = 0.f;
  __syncthreads();
  int gid = blockIdx.x*256 + threadIdx.x;
  float s1 = 0.f, s2 = 0.f;
  int b = 0;
  if (gid < Bz*TF){
    b = gid / TF;
    int p = gid - b*TF;
    size_t base = (size_t)b*CTF + p;
    float v[64];
#pragma unroll
    for (int c = 0; c < 64; c++) v[c] = in[base + (size_t)c*TF];
    for (int o = 0; o < 64; o++){
      float s = bias[o];
      const float4* w4 = (const float4*)&W[o*64];
#pragma unroll
      for (int c = 0; c < 16; c++){
        float4 w = w4[c];
        s += v[4*c]*w.x + v[4*c+1]*w.y + v[4*c+2]*w.z + v[4*c+3]*w.w;
      }
      out[base + (size_t)o*TF] = s;
      s1 += s; s2 += s*s;
    }
  }
  // reduce: wave fast-path when the whole wave shares one batch index
  int blo = __shfl(b, 0, 64), bhi = __shfl(b, 63, 64);
  if (blo == bhi){
    float w1 = wave_sum(s1), w2 = wave_sum(s2);
    if ((threadIdx.x & 63) == 0){ atomicAdd(&bacc[blo*2], w1); atomicAdd(&bacc[blo*2+1], w2); }
  } else {
    atomicAdd(&bacc[b*2], s1); atomicAdd(&bacc[b*2+1], s2);
  }
  __syncthreads();
  if (threadIdx.x < 8 && bacc[threadIdx.x] != 0.f) atomicAdd(&stat[threadIdx.x], bacc[threadIdx.x]);
}

__global__ void k_gnapply(float* __restrict__ y, const float* __restrict__ g,
                          const float* __restrict__ be, const float* __restrict__ a,
                          const float* __restrict__ stat){
  size_t gid = (size_t)blockIdx.x*256 + threadIdx.x;
  if (gid >= (size_t)(SZ/4)) return;
  size_t e0 = gid*4;
  int b = (int)(e0 / CTF);
  int c = (int)((e0 / TF) & 63);
  float mu = stat[b*2] * (1.f/(float)CTF);
  float var = stat[b*2+1] * (1.f/(float)CTF) - mu*mu;
  float rstd = rsqrtf(var + EPSv);
  float gc = g[c], bc = be[c], al = a[0];
  float4 v = *(const float4*)(y + e0);
  float o[4] = {v.x, v.y, v.z, v.w};
#pragma unroll
  for (int i = 0; i < 4; i++){
    float z = (o[i]-mu)*rstd*gc + bc;
    o[i] = z >= 0.f ? z : al*z;
  }
  *(float4*)(y + e0) = make_float4(o[0], o[1], o[2], o[3]);
}

// ---------------- QKV projection, stage P: Z[b][r=0..95][p] = prelu(W y + b), bf16 ----
// rows 0-15: Q(h*4+e), 16-31: K, 32-95: V(h*16+d)
// Weights/bias/alpha via wave-uniform global reads (scalar path) -- no LDS.
// (old LDS version: 1536 uniform ds_read_b128/thread at occupancy 20% = latency-bound)
__global__ __launch_bounds__(256) void k_qkvP(const float* __restrict__ Y,
    const float* __restrict__ qw, const float* __restrict__ qb, const float* __restrict__ qa,
    const float* __restrict__ kw, const float* __restrict__ kb, const float* __restrict__ ka,
    const float* __restrict__ vw, const float* __restrict__ vb, const float* __restrict__ va,
    __hip_bfloat16* __restrict__ Z){
  int gid = blockIdx.x*256 + threadIdx.x;
  if (gid >= Bz*TF) return;
  int b = gid / TF, p = gid - b*TF;
  size_t base = (size_t)b*CTF + p;
  float v[64];
#pragma unroll
  for (int c = 0; c < 64; c++) v[c] = Y[base + (size_t)c*TF];
  __hip_bfloat16* zb = Z + ((size_t)b*96)*TF + p;
  // Q: rows 0-15
  for (int r = 0; r < 16; r++){
    float s = qb[r];
    const float4* w4 = (const float4*)&qw[r*64];
#pragma unroll
    for (int c = 0; c < 16; c++){
      float4 w = w4[c];
      s += v[4*c]*w.x + v[4*c+1]*w.y + v[4*c+2]*w.z + v[4*c+3]*w.w;
    }
    float al = qa[r>>2];
    s = s >= 0.f ? s : al*s;
    zb[(size_t)r*TF] = __float2bfloat16(s);
  }
  // K: rows 16-31
  for (int r = 0; r < 16; r++){
    float s = kb[r];
    const float4* w4 = (const float4*)&kw[r*64];
#pragma unroll
    for (int c = 0; c < 16; c++){
      float4 w = w4[c];
      s += v[4*c]*w.x + v[4*c+1]*w.y + v[4*c+2]*w.z + v[4*c+3]*w.w;
    }
    float al = ka[r>>2];
    s = s >= 0.f ? s : al*s;
    zb[(size_t)(16+r)*TF] = __float2bfloat16(s);
  }
  // V: rows 32-95
  for (int r = 0; r < 64; r++){
    float s = vb[r];
    const float4* w4 = (const float4*)&vw[r*64];
#pragma unroll
    for (int c = 0; c < 16; c++){
      float4 w = w4[c];
      s += v[4*c]*w.x + v[4*c+1]*w.y + v[4*c+2]*w.z + v[4*c+3]*w.w;
    }
    float al = va[r>>4];
    s = s >= 0.f ? s : al*s;
    zb[(size_t)(32+r)*TF] = __float2bfloat16(s);
  }
}

// ---------------- QKV stage N: per-(b,t) LN over (e,f) per (h,kind), write Qm/Km/Vm ----
__global__ __launch_bounds__(256) void k_qkvN(const __hip_bfloat16* __restrict__ Z,
    const float* __restrict__ qg, const float* __restrict__ qz,
    const float* __restrict__ kg, const float* __restrict__ kz,
    const float* __restrict__ vg, const float* __restrict__ vz,
    __hip_bfloat16* __restrict__ Qm, __hip_bfloat16* __restrict__ Km,
    __hip_bfloat16* __restrict__ Vm){
  __shared__ ushort zt[96*129];
  __shared__ float ps1[256], ps2[256];
  __shared__ float mug[12], rsg[12];
  int t = blockIdx.x, b = blockIdx.y;
  const ushort* Zb = (const ushort*)(Z + ((size_t)b*96)*TF + (size_t)t*Ff);
  int tid = threadIdx.x;
  // unit decomposition: 24 units of 516 items; 10 threads per unit (240 active)
  int u = tid/10, l = tid - u*10;
  int kind = 0, h = 0, jbase = 0, g = 0, rbase = 0;
  bool act = tid < 240;
  if (act){
    if (u < 4){ kind = 0; h = u; jbase = 0; g = h; rbase = h*4; }
    else if (u < 8){ kind = 1; h = u-4; jbase = 0; g = 4+h; rbase = 16+h*4; }
    else { int uv = u-8; kind = 2; h = uv>>2; jbase = (uv&3)*516; g = 8+h; rbase = 32+h*16; }
  }
  float s1 = 0.f, s2 = 0.f;
  if (act){
    for (int j = jbase + l; j < jbase + 516; j += 10){
      int e = j/129, f = j - e*129;
      int r = rbase + e;
      ushort raw = Zb[(size_t)r*TF + f];
      float z = bits_f32(raw);
      s1 += z; s2 += z*z;
      zt[r*129 + f] = raw;
    }
  }
  ps1[tid] = s1; ps2[tid] = s2;
  __syncthreads();
  if (tid < 12){
    int t0, cnt; float n;
    if (tid < 8){ t0 = tid*10; cnt = 10; n = 516.f; }
    else { t0 = (8 + (tid-8)*4)*10; cnt = 40; n = 2064.f; }
    float a = 0.f, q = 0.f;
    for (int i = 0; i < cnt; i++){ a += ps1[t0+i]; q += ps2[t0+i]; }
    float mu = a/n;
    mug[tid] = mu;
    rsg[tid] = rsqrtf(q/n - mu*mu + EPSv);
  }
  __syncthreads();
  if (act){
    float mu = mug[g], rs = rsg[g];
    size_t obase = (size_t)(h*Bz + b)*Tt + t;
    const float* lg; const float* lb; __hip_bfloat16* outp;
    if (kind == 0){ lg = qg + h*516; lb = qz + h*516; outp = Qm + obase*KQK; }
    else if (kind == 1){ lg = kg + h*516; lb = kz + h*516; outp = Km + obase*KQK; }
    else { lg = vg + h*2064; lb = vz + h*2064; outp = Vm + obase*NV; }
    for (int j = jbase + l; j < jbase + 516; j += 10){
      int e = j/129, f = j - e*129;
      int r = rbase + e;
      float z = bits_f32(zt[r*129 + f]);
      float val = (z - mu)*rs*lg[j] + lb[j];
      outp[j] = __float2bfloat16(val);
    }
  } else {
    // pad K-dim 516->544 with zeros for Q and K rows (224 pads, 14 per thread)
    int i0 = (tid - 240)*14;
    for (int i = i0; i < i0 + 14; i++){
      int kk = i/112, pj = i - kk*112;
      int hh = pj/28, off = 516 + (pj - hh*28);
      size_t obase = (size_t)(hh*Bz + b)*Tt + t;
      (kk ? Km : Qm)[obase*KQK + off] = __float2bfloat16(0.f);
    }
  }
}

// transpose V: Vm[hb][t][n] -> Vt[hb][n][tp] with tp-stride KPV, zero pad t>=1000
__global__ void k_vt(const ushort* __restrict__ Vm, ushort* __restrict__ Vt){
  __shared__ ushort tile[64][72];
  int t0 = blockIdx.x*64, n0 = blockIdx.y*64, hb = blockIdx.z;
  const ushort* src = Vm + (size_t)hb*Tt*NV;
  ushort* dst = Vt + (size_t)hb*NV*KPV;
  int nl = threadIdx.x & 63, tl = threadIdx.x >> 6;
#pragma unroll
  for (int i = 0; i < 16; i++){
    int t = tl + i*4;
    int gt = t0 + t, gn = n0 + nl;
    ushort v = 0;
    if (gt < Tt && gn < NV) v = src[(size_t)gt*NV + gn];
    tile[t][nl] = v;
  }
  __syncthreads();
  int tl2 = threadIdx.x & 63, nl2 = threadIdx.x >> 6;
#pragma unroll
  for (int i = 0; i < 16; i++){
    int n = nl2 + i*4;
    int gn = n0 + n;
    if (gn < NV) dst[(size_t)gn*KPV + t0 + tl2] = tile[tl2][n];
  }
}

// ---------------- bf16 MFMA GEMM: C[M,N] = A[M,Kc] * B^T[N,Kc]  ----------------
template<int MODE>
__global__ __launch_bounds__(256) void k_gemm(
    const ushort* __restrict__ A, int lda, long strideA,
    const ushort* __restrict__ Bt, int ldb, long strideB,
    float* __restrict__ C, long strideC,
    int M, int N, int Kc, float alpha){
  __shared__ ushort As[128*40];
  __shared__ ushort Bs[128*40];
  int hb = blockIdx.z;
  const ushort* Ab = A + (long)hb*strideA;
  const ushort* Bb = Bt + (long)hb*strideB;
  int i0 = blockIdx.y*128, j0 = blockIdx.x*128;
  int tid = threadIdx.x;
  int wave = tid >> 6, lane = tid & 63;
  int wm = (wave >> 1)*64, wn = (wave & 1)*64;
  int col16 = lane & 15, quad = lane >> 4;
  f32x4 acc[4][4] = {};
  int srow = tid >> 2;
  int scol = (tid & 3)*8;
  for (int k0 = 0; k0 < Kc; k0 += 32){
#pragma unroll
    for (int r = 0; r < 2; r++){
      int row = srow + r*64;
      int gi = i0 + row;
      float4 va = (gi < M) ? *(const float4*)(Ab + (long)gi*lda + k0 + scol)
                           : make_float4(0.f,0.f,0.f,0.f);
      *(float4*)&As[row*40 + scol] = va;
      int gj = j0 + row;
      float4 vb = (gj < N) ? *(const float4*)(Bb + (long)gj*ldb + k0 + scol)
                           : make_float4(0.f,0.f,0.f,0.f);
      *(float4*)&Bs[row*40 + scol] = vb;
    }
    __syncthreads();
    bf16x8 af[4], bfr[4];
#pragma unroll
    for (int mt = 0; mt < 4; mt++) af[mt]  = *(const bf16x8*)&As[(wm + mt*16 + col16)*40 + quad*8];
#pragma unroll
    for (int nt = 0; nt < 4; nt++) bfr[nt] = *(const bf16x8*)&Bs[(wn + nt*16 + col16)*40 + quad*8];
#pragma unroll
    for (int mt = 0; mt < 4; mt++)
#pragma unroll
      for (int nt = 0; nt < 4; nt++)
        acc[mt][nt] = __builtin_amdgcn_mfma_f32_16x16x32_bf16(af[mt], bfr[nt], acc[mt][nt], 0, 0, 0);
    __syncthreads();
  }
  if (MODE == 0){
    float* Cb = C + (long)hb*strideC;
#pragma unroll
    for (int mt = 0; mt < 4; mt++){
      int ibase = i0 + wm + mt*16 + quad*4;
#pragma unroll
      for (int nt = 0; nt < 4; nt++){
        int j = j0 + wn + nt*16 + col16;
        if (j < N){
#pragma unroll
          for (int rg = 0; rg < 4; rg++){
            int i = ibase + rg;
            if (i < M) Cb[(long)i*N + j] = acc[mt][nt][rg]*alpha;
          }
        }
      }
    }
  } else {
    int h = hb >> 2, b = hb & 3;
#pragma unroll
    for (int mt = 0; mt < 4; mt++){
      int ibase = i0 + wm + mt*16 + quad*4;
#pragma unroll
      for (int nt = 0; nt < 4; nt++){
        int n = j0 + wn + nt*16 + col16;
        if (n < NV){
          int d = n / 129, f = n - d*129;
          float* oc = C + ((long)(b*64 + h*16 + d)*Tt)*Ff + f;
#pragma unroll
          for (int rg = 0; rg < 4; rg++){
            int i = ibase + rg;
            if (i < M) oc[(long)i*Ff] = acc[mt][nt][rg];
          }
        }
      }
    }
  }
}

// softmax over row of 1000 f32; writes P bf16 (padded to 1024, zeros) in place
__global__ void k_softmax(float* __restrict__ S){
  float* row = S + (size_t)blockIdx.x * Tt;
  __hip_bfloat16* prow = (__hip_bfloat16*)row;
  int tid = threadIdx.x;
  __shared__ float red[4];
  float lv[4];
#pragma unroll
  for (int k = 0; k < 4; k++){ int idx = tid + k*256; lv[k] = (idx < Tt) ? row[idx] : -1e30f; }
  float m = fmaxf(fmaxf(lv[0], lv[1]), fmaxf(lv[2], lv[3]));
  m = blk_max256(m, red);
  float s = 0.f;
#pragma unroll
  for (int k = 0; k < 4; k++){ lv[k] = __expf(lv[k]-m); s += lv[k]; }
  s = blk_sum256(s, red);
  float inv = 1.f/s;
#pragma unroll
  for (int k = 0; k < 4; k++){
    int idx = tid + k*256;
    prow[idx] = __float2bfloat16(idx < Tt ? lv[k]*inv : 0.f);
  }
}

// ---------------- proj stage A: 1x1 conv 64->64 + bias + prelu, write to scratch,
// accumulate per-(b,t) sum/sumsq via segmented wave reduction + global atomics.
// Weights via wave-uniform global reads (scalar path), input column in VGPRs.
__global__ __launch_bounds__(256) void k_projA(const float* __restrict__ in, float* __restrict__ out,
    const float* __restrict__ W, const float* __restrict__ bias,
    const float* __restrict__ pa, float* __restrict__ pstat){
  int gid = blockIdx.x*256 + threadIdx.x;
  float s1 = 0.f, s2 = 0.f;
  int r = 3999;
  if (gid < Bz*TF){
    int b = gid / TF;
    int p = gid - b*TF;
    r = gid / 129;        // = b*1000 + t  (since TF = 1000*129)
    size_t base = (size_t)b*CTF + p;
    float al = pa[0];
    float v[64];
#pragma unroll
    for (int c = 0; c < 64; c++) v[c] = in[base + (size_t)c*TF];
    for (int o = 0; o < 64; o++){
      float s = bias[o];
      const float4* w4 = (const float4*)&W[o*64];
#pragma unroll
      for (int c = 0; c < 16; c++){
        float4 w = w4[c];
        s += v[4*c]*w.x + v[4*c+1]*w.y + v[4*c+2]*w.z + v[4*c+3]*w.w;
      }
      s = s >= 0.f ? s : al*s;
      out[base + (size_t)o*TF] = s;
      s1 += s; s2 += s*s;
    }
  }
  // per-(b,t) row stats; a wave (64 consecutive gids) spans at most 2 rows of 129
  int rlo = __shfl(r, 0, 64), rhi = __shfl(r, 63, 64);
  if (rlo == rhi){
    float a1 = wave_sum(s1), a2 = wave_sum(s2);
    if ((threadIdx.x & 63) == 0){
      atomicAdd(&pstat[rlo*2], a1); atomicAdd(&pstat[rlo*2+1], a2);
    }
  } else {
    bool lo = (r == rlo);
    float a1 = wave_sum(lo ? s1 : 0.f);
    float a2 = wave_sum(lo ? s2 : 0.f);
    float b1 = wave_sum(lo ? 0.f : s1);
    float b2 = wave_sum(lo ? 0.f : s2);
    if ((threadIdx.x & 63) == 0){
      atomicAdd(&pstat[rlo*2], a1); atomicAdd(&pstat[rlo*2+1], a2);
      atomicAdd(&pstat[rhi*2], b1); atomicAdd(&pstat[rhi*2+1], b2);
    }
  }
}

// ---------------- proj stage B: LN over (c,f) per (b,t) + residual, final write ----
__global__ __launch_bounds__(256) void k_projB(const float* __restrict__ proj,
    const float* __restrict__ Y, float* __restrict__ Out,
    const float* __restrict__ pstat, const float* __restrict__ lng,
    const float* __restrict__ lnb){
  int t = blockIdx.x, b = blockIdx.y;
  int r = b*1000 + t;
  const float n = 64.f*129.f;
  float mu = pstat[r*2] / n;
  float var = pstat[r*2+1] / n - mu*mu;
  float rstd = rsqrtf(var + EPSv);
  size_t base = (size_t)b*CTF + (size_t)t*Ff;
  for (int idx = threadIdx.x; idx < 64*Ff; idx += 256){
    int c = idx / Ff, f = idx - c*Ff;
    size_t off = base + (size_t)c*TF + f;
    Out[off] = (proj[off]-mu)*rstd*lng[idx] + lnb[idx] + Y[off];
  }
}

extern "C" void kernel_launch(void* const* d_in, const int* in_sizes, int n_in,
                              void* d_out, int out_size, void* d_ws, size_t ws_size,
                              hipStream_t stream){
  const float* x       = (const float*)d_in[0];
  const float* br_g    = (const float*)d_in[1];
  const float* br_b    = (const float*)d_in[2];
  const float* lisa_w  = (const float*)d_in[3];
  const float* lisa_in = (const float*)d_in[4];
  const float* lisa_ll = (const float*)d_in[5];
  const float* lisa_lh = (const float*)d_in[6];
  const float* mix_g   = (const float*)d_in[7];
  const float* mix_b   = (const float*)d_in[8];
  const float* convb_w = (const float*)d_in[9];
  const float* convb_b = (const float*)d_in[10];
  const float* gn_g    = (const float*)d_in[11];
  const float* gn_b    = (const float*)d_in[12];
  const float* convb_a = (const float*)d_in[13];
  const float* q_w  = (const float*)d_in[14];
  const float* q_b  = (const float*)d_in[15];
  const float* q_a  = (const float*)d_in[16];
  const float* q_lg = (const float*)d_in[17];
  const float* q_lb = (const float*)d_in[18];
  const float* k_w  = (const float*)d_in[19];
  const float* k_b  = (const float*)d_in[20];
  const float* k_a  = (const float*)d_in[21];
  const float* k_lg = (const float*)d_in[22];
  const float* k_lb = (const float*)d_in[23];
  const float* v_w  = (const float*)d_in[24];
  const float* v_b  = (const float*)d_in[25];
  const float* v_a  = (const float*)d_in[26];
  const float* v_lg = (const float*)d_in[27];
  const float* v_lb = (const float*)d_in[28];
  const float* p_w  = (const float*)d_in[29];
  const float* p_b  = (const float*)d_in[30];
  const float* p_a  = (const float*)d_in[31];
  const float* p_lg = (const float*)d_in[32];
  const float* p_lb = (const float*)d_in[33];

  float* out  = (float*)d_out;
  float* buf0 = (float*)d_ws;          // bsum -> Z -> Vt|S -> proj scratch
  float* buf1 = buf0 + SZ;             // ln temp -> Y ("output")
  float* buf2 = buf1 + SZ;             // lisa_h temp -> Qm|Km|Vm (bf16)
  float* chm  = buf2 + SZ;             // 6*256 channel-sum sections (one per ln4d stage)
  float* filt = chm + 1536;            // 48 (pad 64)
  float* stat = filt + 64;             // 8  (pad 16)
  float* gapv = stat + 16;             // 33024 (lisa loop only)
  float* pstat = gapv;                 // 8000 -- ALIASES gapv (dead after lisa loop);
                                       // zeroed by k_zerop right before k_projA

  if (ws_size < (3*(size_t)SZ + 40000)*sizeof(float)) return;

  __hip_bfloat16* Qm = (__hip_bfloat16*)buf2;                 // 16*1000*544
  __hip_bfloat16* Km = Qm + (size_t)16*Tt*KQK;                // 16*1000*544
  __hip_bfloat16* Vm = Km + (size_t)16*Tt*KQK;                // 16*1000*2064
  __hip_bfloat16* Z  = (__hip_bfloat16*)buf0;                 // 4*96*129000 bf16 (99 MB)
  ushort* Vt = (ushort*)buf0;                                 // 16*2064*1024 bf16 (after Z dead)
  float*  S  = buf0 + (size_t)16*NV*KPV/2;                    // 16*1000*1000 f32

  k_zeroinit<<<8, 256, 0, stream>>>(stat, chm);

  const int dils[3] = {3, 5, 7};
  for (int i = 0; i < 3; i++){
    k_ln4d<<<2016, 256, 0, stream>>>(x, buf1, br_g + i*64, br_b + i*64, chm + i*256);
    k_filt<<<1, 64, 0, stream>>>(chm + i*256, lisa_w + i*768, filt);
    k_lisa_h<<<Bz*Cc*Tt, 64, 0, stream>>>(buf1, buf2, filt, lisa_in + i*64, lisa_ll + i*64, lisa_lh + i*64, dils[i]);
    k_ln4d<<<2016, 256, 0, stream>>>(buf2, buf1, br_g + (i+3)*64, br_b + (i+3)*64, chm + (3+i)*256);
    k_filt<<<1, 64, 0, stream>>>(chm + (3+i)*256, lisa_w + (i+3)*768, filt);
    k_colmean<<<dim3(3, 64, 4), 256, 0, stream>>>(buf1, gapv);
    k_lisa_v<<<dim3(30, 64, 4), 256, 0, stream>>>(buf1, x, buf0, filt, gapv,
        lisa_in + (i+3)*64, lisa_ll + (i+3)*64, lisa_lh + (i+3)*64,
        mix_g + i*64, mix_b + i*64, dils[i], i > 0 ? 1 : 0);
  }
  k_convb<<<2016, 256, 0, stream>>>(buf0, buf1, convb_w, convb_b, stat);
  k_gnapply<<<32250, 256, 0, stream>>>(buf1, gn_g, gn_b, convb_a, stat);
  k_qkvP<<<2016, 256, 0, stream>>>(buf1, q_w, q_b, q_a, k_w, k_b, k_a, v_w, v_b, v_a, Z);
  k_qkvN<<<dim3(1000, 4), 256, 0, stream>>>(Z, q_lg, q_lb, k_lg, k_lb, v_lg, v_lb, Qm, Km, Vm);
  k_vt<<<dim3(16, 33, 16), 256, 0, stream>>>((const ushort*)Vm, Vt);
  k_gemm<0><<<dim3(8, 8, 16), 256, 0, stream>>>(
      (const ushort*)Qm, KQK, (long)Tt*KQK,
      (const ushort*)Km, KQK, (long)Tt*KQK,
      S, (long)Tt*Tt, Tt, Tt, KQK, 0.04402254531f);
  k_softmax<<<16000, 256, 0, stream>>>(S);
  k_gemm<1><<<dim3(17, 8, 16), 256, 0, stream>>>(
      (const ushort*)S, LDP, (long)Tt*LDP,
      Vt, KPV, (long)NV*KPV,
      out, 0, Tt, NV, KPV, 1.f);
  // proj: conv+prelu+stats into buf0 (free after attention), then LN+residual into out
  k_zerop<<<32, 256, 0, stream>>>(pstat);
  k_projA<<<2016, 256, 0, stream>>>(out, buf0, p_w, p_b, p_a, pstat);
  k_projB<<<dim3(1000, 4), 256, 0, stream>>>(buf0, buf1, out, pstat, p_lg, p_lb);
}

// Round 5
// 4304.506 us; speedup vs baseline: 2.5567x; 2.5567x over previous
//
#include <hip/hip_runtime.h>
#include <hip/hip_bf16.h>

#define Bz 4
#define Cc 64
#define Tt 1000
#define Ff 129
#define TF 129000            // Tt*Ff
#define CTF 8256000          // Cc*TF
#define SZ 33024000L         // Bz*CTF
#define EPSv 1e-5f

#define KQK 544              // 516 padded to mult of 32
#define KPV 1024             // 1000 padded
#define LDP 2000             // P row stride in bf16 (= 1000 f32 reused in place)
#define NV 2064              // 16*129

typedef __attribute__((ext_vector_type(8))) short bf16x8;
typedef __attribute__((ext_vector_type(4))) float f32x4;

// bf16 <-> bits helpers (no .data member on this ROCm's __hip_bfloat16)
__device__ __forceinline__ ushort bf_bits(__hip_bfloat16 h){
  union { __hip_bfloat16 h; ushort u; } c; c.h = h; return c.u;
}
__device__ __forceinline__ float bits_f32(ushort u){
  union { float f; unsigned int i; } c; c.i = ((unsigned int)u) << 16; return c.f;
}

// ---------------- reduction helpers ----------------
__device__ __forceinline__ float wave_sum(float v){
#pragma unroll
  for (int o = 32; o; o >>= 1) v += __shfl_down(v, o, 64);
  return v;
}
__device__ __forceinline__ float wave_bcast_sum(float v){
#pragma unroll
  for (int o = 1; o < 64; o <<= 1) v += __shfl_xor(v, o, 64);
  return v;
}
__device__ __forceinline__ float blk_sum256(float v, float* red){
  __syncthreads();
  v = wave_sum(v);
  int tid = threadIdx.x;
  if ((tid & 63) == 0) red[tid >> 6] = v;
  __syncthreads();
  return red[0] + red[1] + red[2] + red[3];
}
__device__ __forceinline__ float blk_max256(float v, float* red){
  __syncthreads();
#pragma unroll
  for (int o = 32; o; o >>= 1) v = fmaxf(v, __shfl_down(v, o, 64));
  int tid = threadIdx.x;
  if ((tid & 63) == 0) red[tid >> 6] = v;
  __syncthreads();
  return fmaxf(fmaxf(red[0], red[1]), fmaxf(red[2], red[3]));
}

// ---------------- misc ----------------
// zero stat[8] + chm[6*256] once at start (each ln4d stage owns one chm section)
__global__ void k_zeroinit(float* stat, float* chm){
  int i = blockIdx.x*256 + threadIdx.x;
  if (i < 8) stat[i] = 0.f;
  if (i < 1536) chm[i] = 0.f;
}
// zero pstat[8000] (aliases gapv; must run AFTER the lisa loop, before k_projA)
__global__ void k_zerop(float* ps){
  int i = blockIdx.x*256 + threadIdx.x;
  if (i < 8000) ps[i] = 0.f;
}

// ln4d: LN over channel axis per (b,t,f); std = sqrt(max(var, EPS))
// Fused per-(b,c) channel-SUM accumulation (replaces the k_chmean re-read pass).
// CRITICAL (round-4 post-mortem): every access to v[] must be compile-time
// static -- one runtime-indexed loop (the old un-unrolled fallback) forced the
// whole array to scratch (VGPR=76, VALUBusy 0.9%, 1565us). All loops unrolled.
// Fast path is block-uniform (2012/2016 blocks): wave_sum per channel -> LDS ->
// one global atomic per channel per BLOCK (4x fewer atomics than per-wave).
__global__ __launch_bounds__(256) void k_ln4d(const float* __restrict__ in, float* __restrict__ out,
                       const float* __restrict__ g, const float* __restrict__ be,
                       float* __restrict__ chm){
  __shared__ float cred[256];
  int gid = blockIdx.x*256 + threadIdx.x;
  int gs = blockIdx.x*256;
  int b0 = gs / TF;
  bool fastblk = (gs + 255 < Bz*TF) && ((gs + 255) / TF == b0);  // block-uniform
  bool valid = gid < Bz*TF;
  int b = 0;
  float v[64];
  if (valid){
    b = gid / TF;
    int p = gid - b*TF;
    size_t base = (size_t)b*CTF + p;
    float s1 = 0.f, s2 = 0.f;
#pragma unroll
    for (int c = 0; c < 64; c++){ float x = in[base + (size_t)c*TF]; v[c] = x; s1 += x; s2 += x*x; }
    float mu = s1*(1.f/64.f);
    float var = s2*(1.f/64.f) - mu*mu;
    float rstd = rsqrtf(fmaxf(var, EPSv));
#pragma unroll
    for (int c = 0; c < 64; c++){
      float o = (v[c]-mu)*rstd*g[c] + be[c];
      v[c] = o;
      out[base + (size_t)c*TF] = o;
    }
  } else {
#pragma unroll
    for (int c = 0; c < 64; c++) v[c] = 0.f;
  }
  if (fastblk){
    int wave = threadIdx.x >> 6, lane = threadIdx.x & 63;
#pragma unroll
    for (int c = 0; c < 64; c++){
      float s = wave_sum(v[c]);
      if (lane == 0) cred[wave*64 + c] = s;
    }
    __syncthreads();
    if (threadIdx.x < 64){
      float tot = cred[threadIdx.x] + cred[threadIdx.x+64] + cred[threadIdx.x+128] + cred[threadIdx.x+192];
      atomicAdd(&chm[b0*64 + threadIdx.x], tot);
    }
  } else if (valid){
#pragma unroll
    for (int c = 0; c < 64; c++) atomicAdd(&chm[b*64 + c], v[c]);
  }
}

// filt from channel SUMS (1/TF folded in before tanh; linear so exact)
__global__ void k_filt(const float* __restrict__ m, const float* __restrict__ w, float* __restrict__ filt){
  int t = threadIdx.x;
  if (t >= Bz*12) return;
  int b = t/12, gk = t - b*12;
  float s = 0.f;
  for (int c = 0; c < 64; c++) s += m[b*64+c]*w[gk*64+c];
  filt[t] = tanhf(s * (1.f/(float)TF));
}

// lisa horizontal: one wave per (b,c,t) row of 129
__global__ void k_lisa_h(const float* __restrict__ in, float* __restrict__ out,
                         const float* __restrict__ filt, const float* __restrict__ iap,
                         const float* __restrict__ llp, const float* __restrict__ lhp, int dil){
  __shared__ float r[132];
  int row = blockIdx.x;
  int c = (row / Tt) % Cc;
  int b = row / (Tt*Cc);
  size_t base = (size_t)row * Ff;
  int lane = threadIdx.x;
  float s = 0.f;
  for (int f = lane; f < Ff; f += 64){ float x = in[base+f]; r[f] = x; s += x; }
  s = wave_bcast_sum(s);
  float gap = s * (1.f/129.f);
  __syncthreads();
  int g3 = b*12 + (c>>4)*3;
  float w0 = filt[g3], w1 = filt[g3+1], w2 = filt[g3+2];
  float ia = iap[c], ll = llp[c], lh1 = lhp[c] + 1.f, ia1 = ia + 1.f;
  for (int f = lane; f < Ff; f += 64){
    int fm = f - dil; fm = fm < 0 ? -fm : fm;
    int fp = f + dil; fp = fp > 128 ? 256 - fp : fp;
    float conv = w0*r[fm] + w1*r[f] + w2*r[fp];
    out[base+f] = (conv*ia1 - ia*gap)*ll + r[f]*lh1;
  }
}

// column means over t per (b,c,f)
__global__ void k_colmean(const float* __restrict__ in, float* __restrict__ gapv){
  int lane = threadIdx.x & 63, strip = threadIdx.x >> 6;
  int f = blockIdx.x*64 + lane;
  int c = blockIdx.y, b = blockIdx.z;
  size_t cb = ((size_t)(b*Cc + c))*TF + f;
  float s = 0.f;
  if (f < Ff){ for (int t = strip; t < Tt; t += 4) s += in[cb + (size_t)t*Ff]; }
  __shared__ float sm[256];
  sm[threadIdx.x] = s; __syncthreads();
  if (strip == 0 && f < Ff){
    float tot = sm[threadIdx.x] + sm[threadIdx.x+64] + sm[threadIdx.x+128] + sm[threadIdx.x+192];
    gapv[(b*Cc + c)*Ff + f] = tot * (1.f/(float)Tt);
  }
}

// lisa vertical fused with bsum accumulate
__global__ void k_lisa_v(const float* __restrict__ in, const float* __restrict__ x,
                         float* __restrict__ A, const float* __restrict__ filt,
                         const float* __restrict__ gapv,
                         const float* __restrict__ iap, const float* __restrict__ llp,
                         const float* __restrict__ lhp,
                         const float* __restrict__ mgp, const float* __restrict__ mbp,
                         int dil, int accum){
  int lane = threadIdx.x & 63, strip = threadIdx.x >> 6;
  int ftile = blockIdx.x % 3, tch = blockIdx.x / 3;
  int f = ftile*64 + lane;
  if (f >= Ff) return;
  int c = blockIdx.y, b = blockIdx.z;
  int g3 = b*12 + (c>>4)*3;
  float w0 = filt[g3], w1 = filt[g3+1], w2 = filt[g3+2];
  float ia = iap[c], ll = llp[c], lh1 = lhp[c]+1.f, ia1 = ia+1.f;
  float mg = mgp[c], mb = mbp[c];
  float gap = gapv[(b*Cc+c)*Ff + f];
  size_t cb = ((size_t)(b*Cc + c))*TF + f;
  int tend = tch*100 + 100;
  for (int t = tch*100 + strip; t < tend; t += 4){
    int tm = t - dil; tm = tm < 0 ? -tm : tm;
    int tp = t + dil; tp = tp > 999 ? 1998 - tp : tp;
    float vm = in[cb + (size_t)tm*Ff];
    float vc = in[cb + (size_t)t*Ff];
    float vp = in[cb + (size_t)tp*Ff];
    float conv = w0*vm + w1*vc + w2*vp;
    float val = (conv*ia1 - ia*gap)*ll + vc*lh1;
    float o = mg*val + mb*x[cb + (size_t)t*Ff];
    size_t oi = cb + (size_t)t*Ff;
    A[oi] = accum ? (A[oi] + o) : o;
  }
}

// 1x1 conv 64->64, fused with per-batch global stats (sum, sumsq) for the
// following GroupNorm. stat must be zeroed before this launch.
// Weights read directly from global with wave-uniform addresses (scalar-load path).
__global__ __launch_bounds__(256) void k_convb(const float* __restrict__ in, float* __restrict__ out,
                        const float* __restrict__ W, const float* __restrict__ bias,
                        float* __restrict__ stat){
  __shared__ float bacc[8];
  if (threadIdx.x < 8) bacc[threadIdx.x] = 0.f;
  __syncthreads();
  int gid = blockIdx.x*256 + threadIdx.x;
  float s1 = 0.f, s2 = 0.f;
  int b = 0;
  if (gid < Bz*TF){
    b = gid / TF;
    int p = gid - b*TF;
    size_t base = (size_t)b*CTF + p;
    float v[64];
#pragma unroll
    for (int c = 0; c < 64; c++) v[c] = in[base + (size_t)c*TF];
    for (int o = 0; o < 64; o++){
      float s = bias[o];
      const float4* w4 = (const float4*)&W[o*64];
#pragma unroll
      for (int c = 0; c < 16; c++){
        float4 w = w4[c];
        s += v[4*c]*w.x + v[4*c+1]*w.y + v[4*c+2]*w.z + v[4*c+3]*w.w;
      }
      out[base + (size_t)o*TF] = s;
      s1 += s; s2 += s*s;
    }
  }
  // reduce: wave fast-path when the whole wave shares one batch index
  int blo = __shfl(b, 0, 64), bhi = __shfl(b, 63, 64);
  if (blo == bhi){
    float w1 = wave_sum(s1), w2 = wave_sum(s2);
    if ((threadIdx.x & 63) == 0){ atomicAdd(&bacc[blo*2], w1); atomicAdd(&bacc[blo*2+1], w2); }
  } else {
    atomicAdd(&bacc[b*2], s1); atomicAdd(&bacc[b*2+1], s2);
  }
  __syncthreads();
  if (threadIdx.x < 8 && bacc[threadIdx.x] != 0.f) atomicAdd(&stat[threadIdx.x], bacc[threadIdx.x]);
}

__global__ void k_gnapply(float* __restrict__ y, const float* __restrict__ g,
                          const float* __restrict__ be, const float* __restrict__ a,
                          const float* __restrict__ stat){
  size_t gid = (size_t)blockIdx.x*256 + threadIdx.x;
  if (gid >= (size_t)(SZ/4)) return;
  size_t e0 = gid*4;
  int b = (int)(e0 / CTF);
  int c = (int)((e0 / TF) & 63);
  float mu = stat[b*2] * (1.f/(float)CTF);
  float var = stat[b*2+1] * (1.f/(float)CTF) - mu*mu;
  float rstd = rsqrtf(var + EPSv);
  float gc = g[c], bc = be[c], al = a[0];
  float4 v = *(const float4*)(y + e0);
  float o[4] = {v.x, v.y, v.z, v.w};
#pragma unroll
  for (int i = 0; i < 4; i++){
    float z = (o[i]-mu)*rstd*gc + bc;
    o[i] = z >= 0.f ? z : al*z;
  }
  *(float4*)(y + e0) = make_float4(o[0], o[1], o[2], o[3]);
}

// ---------------- QKV projection, stage P: Z[b][r=0..95][p] = prelu(W y + b), bf16 ----
// rows 0-15: Q(h*4+e), 16-31: K, 32-95: V(h*16+d)
// Weights/bias/alpha via wave-uniform global reads (scalar path) -- no LDS.
__global__ __launch_bounds__(256) void k_qkvP(const float* __restrict__ Y,
    const float* __restrict__ qw, const float* __restrict__ qb, const float* __restrict__ qa,
    const float* __restrict__ kw, const float* __restrict__ kb, const float* __restrict__ ka,
    const float* __restrict__ vw, const float* __restrict__ vb, const float* __restrict__ va,
    __hip_bfloat16* __restrict__ Z){
  int gid = blockIdx.x*256 + threadIdx.x;
  if (gid >= Bz*TF) return;
  int b = gid / TF, p = gid - b*TF;
  size_t base = (size_t)b*CTF + p;
  float v[64];
#pragma unroll
  for (int c = 0; c < 64; c++) v[c] = Y[base + (size_t)c*TF];
  __hip_bfloat16* zb = Z + ((size_t)b*96)*TF + p;
  // Q: rows 0-15
  for (int r = 0; r < 16; r++){
    float s = qb[r];
    const float4* w4 = (const float4*)&qw[r*64];
#pragma unroll
    for (int c = 0; c < 16; c++){
      float4 w = w4[c];
      s += v[4*c]*w.x + v[4*c+1]*w.y + v[4*c+2]*w.z + v[4*c+3]*w.w;
    }
    float al = qa[r>>2];
    s = s >= 0.f ? s : al*s;
    zb[(size_t)r*TF] = __float2bfloat16(s);
  }
  // K: rows 16-31
  for (int r = 0; r < 16; r++){
    float s = kb[r];
    const float4* w4 = (const float4*)&kw[r*64];
#pragma unroll
    for (int c = 0; c < 16; c++){
      float4 w = w4[c];
      s += v[4*c]*w.x + v[4*c+1]*w.y + v[4*c+2]*w.z + v[4*c+3]*w.w;
    }
    float al = ka[r>>2];
    s = s >= 0.f ? s : al*s;
    zb[(size_t)(16+r)*TF] = __float2bfloat16(s);
  }
  // V: rows 32-95
  for (int r = 0; r < 64; r++){
    float s = vb[r];
    const float4* w4 = (const float4*)&vw[r*64];
#pragma unroll
    for (int c = 0; c < 16; c++){
      float4 w = w4[c];
      s += v[4*c]*w.x + v[4*c+1]*w.y + v[4*c+2]*w.z + v[4*c+3]*w.w;
    }
    float al = va[r>>4];
    s = s >= 0.f ? s : al*s;
    zb[(size_t)(32+r)*TF] = __float2bfloat16(s);
  }
}

// ---------------- QKV stage N: per-(b,t) LN over (e,f) per (h,kind), write Qm/Km/Vm ----
__global__ __launch_bounds__(256) void k_qkvN(const __hip_bfloat16* __restrict__ Z,
    const float* __restrict__ qg, const float* __restrict__ qz,
    const float* __restrict__ kg, const float* __restrict__ kz,
    const float* __restrict__ vg, const float* __restrict__ vz,
    __hip_bfloat16* __restrict__ Qm, __hip_bfloat16* __restrict__ Km,
    __hip_bfloat16* __restrict__ Vm){
  __shared__ ushort zt[96*129];
  __shared__ float ps1[256], ps2[256];
  __shared__ float mug[12], rsg[12];
  int t = blockIdx.x, b = blockIdx.y;
  const ushort* Zb = (const ushort*)(Z + ((size_t)b*96)*TF + (size_t)t*Ff);
  int tid = threadIdx.x;
  // unit decomposition: 24 units of 516 items; 10 threads per unit (240 active)
  int u = tid/10, l = tid - u*10;
  int kind = 0, h = 0, jbase = 0, g = 0, rbase = 0;
  bool act = tid < 240;
  if (act){
    if (u < 4){ kind = 0; h = u; jbase = 0; g = h; rbase = h*4; }
    else if (u < 8){ kind = 1; h = u-4; jbase = 0; g = 4+h; rbase = 16+h*4; }
    else { int uv = u-8; kind = 2; h = uv>>2; jbase = (uv&3)*516; g = 8+h; rbase = 32+h*16; }
  }
  float s1 = 0.f, s2 = 0.f;
  if (act){
    for (int j = jbase + l; j < jbase + 516; j += 10){
      int e = j/129, f = j - e*129;
      int r = rbase + e;
      ushort raw = Zb[(size_t)r*TF + f];
      float z = bits_f32(raw);
      s1 += z; s2 += z*z;
      zt[r*129 + f] = raw;
    }
  }
  ps1[tid] = s1; ps2[tid] = s2;
  __syncthreads();
  if (tid < 12){
    int t0, cnt; float n;
    if (tid < 8){ t0 = tid*10; cnt = 10; n = 516.f; }
    else { t0 = (8 + (tid-8)*4)*10; cnt = 40; n = 2064.f; }
    float a = 0.f, q = 0.f;
    for (int i = 0; i < cnt; i++){ a += ps1[t0+i]; q += ps2[t0+i]; }
    float mu = a/n;
    mug[tid] = mu;
    rsg[tid] = rsqrtf(q/n - mu*mu + EPSv);
  }
  __syncthreads();
  if (act){
    float mu = mug[g], rs = rsg[g];
    size_t obase = (size_t)(h*Bz + b)*Tt + t;
    const float* lg; const float* lb; __hip_bfloat16* outp;
    if (kind == 0){ lg = qg + h*516; lb = qz + h*516; outp = Qm + obase*KQK; }
    else if (kind == 1){ lg = kg + h*516; lb = kz + h*516; outp = Km + obase*KQK; }
    else { lg = vg + h*2064; lb = vz + h*2064; outp = Vm + obase*NV; }
    for (int j = jbase + l; j < jbase + 516; j += 10){
      int e = j/129, f = j - e*129;
      int r = rbase + e;
      float z = bits_f32(zt[r*129 + f]);
      float val = (z - mu)*rs*lg[j] + lb[j];
      outp[j] = __float2bfloat16(val);
    }
  } else {
    // pad K-dim 516->544 with zeros for Q and K rows (224 pads, 14 per thread)
    int i0 = (tid - 240)*14;
    for (int i = i0; i < i0 + 14; i++){
      int kk = i/112, pj = i - kk*112;
      int hh = pj/28, off = 516 + (pj - hh*28);
      size_t obase = (size_t)(hh*Bz + b)*Tt + t;
      (kk ? Km : Qm)[obase*KQK + off] = __float2bfloat16(0.f);
    }
  }
}

// transpose V: Vm[hb][t][n] -> Vt[hb][n][tp] with tp-stride KPV, zero pad t>=1000
__global__ void k_vt(const ushort* __restrict__ Vm, ushort* __restrict__ Vt){
  __shared__ ushort tile[64][72];
  int t0 = blockIdx.x*64, n0 = blockIdx.y*64, hb = blockIdx.z;
  const ushort* src = Vm + (size_t)hb*Tt*NV;
  ushort* dst = Vt + (size_t)hb*NV*KPV;
  int nl = threadIdx.x & 63, tl = threadIdx.x >> 6;
#pragma unroll
  for (int i = 0; i < 16; i++){
    int t = tl + i*4;
    int gt = t0 + t, gn = n0 + nl;
    ushort v = 0;
    if (gt < Tt && gn < NV) v = src[(size_t)gt*NV + gn];
    tile[t][nl] = v;
  }
  __syncthreads();
  int tl2 = threadIdx.x & 63, nl2 = threadIdx.x >> 6;
#pragma unroll
  for (int i = 0; i < 16; i++){
    int n = nl2 + i*4;
    int gn = n0 + n;
    if (gn < NV) dst[(size_t)gn*KPV + t0 + tl2] = tile[tl2][n];
  }
}

// ---------------- bf16 MFMA GEMM: C[M,N] = A[M,Kc] * B^T[N,Kc]  ----------------
template<int MODE>
__global__ __launch_bounds__(256) void k_gemm(
    const ushort* __restrict__ A, int lda, long strideA,
    const ushort* __restrict__ Bt, int ldb, long strideB,
    float* __restrict__ C, long strideC,
    int M, int N, int Kc, float alpha){
  __shared__ ushort As[128*40];
  __shared__ ushort Bs[128*40];
  int hb = blockIdx.z;
  const ushort* Ab = A + (long)hb*strideA;
  const ushort* Bb = Bt + (long)hb*strideB;
  int i0 = blockIdx.y*128, j0 = blockIdx.x*128;
  int tid = threadIdx.x;
  int wave = tid >> 6, lane = tid & 63;
  int wm = (wave >> 1)*64, wn = (wave & 1)*64;
  int col16 = lane & 15, quad = lane >> 4;
  f32x4 acc[4][4] = {};
  int srow = tid >> 2;
  int scol = (tid & 3)*8;
  for (int k0 = 0; k0 < Kc; k0 += 32){
#pragma unroll
    for (int r = 0; r < 2; r++){
      int row = srow + r*64;
      int gi = i0 + row;
      float4 va = (gi < M) ? *(const float4*)(Ab + (long)gi*lda + k0 + scol)
                           : make_float4(0.f,0.f,0.f,0.f);
      *(float4*)&As[row*40 + scol] = va;
      int gj = j0 + row;
      float4 vb = (gj < N) ? *(const float4*)(Bb + (long)gj*ldb + k0 + scol)
                           : make_float4(0.f,0.f,0.f,0.f);
      *(float4*)&Bs[row*40 + scol] = vb;
    }
    __syncthreads();
    bf16x8 af[4], bfr[4];
#pragma unroll
    for (int mt = 0; mt < 4; mt++) af[mt]  = *(const bf16x8*)&As[(wm + mt*16 + col16)*40 + quad*8];
#pragma unroll
    for (int nt = 0; nt < 4; nt++) bfr[nt] = *(const bf16x8*)&Bs[(wn + nt*16 + col16)*40 + quad*8];
#pragma unroll
    for (int mt = 0; mt < 4; mt++)
#pragma unroll
      for (int nt = 0; nt < 4; nt++)
        acc[mt][nt] = __builtin_amdgcn_mfma_f32_16x16x32_bf16(af[mt], bfr[nt], acc[mt][nt], 0, 0, 0);
    __syncthreads();
  }
  if (MODE == 0){
    float* Cb = C + (long)hb*strideC;
#pragma unroll
    for (int mt = 0; mt < 4; mt++){
      int ibase = i0 + wm + mt*16 + quad*4;
#pragma unroll
      for (int nt = 0; nt < 4; nt++){
        int j = j0 + wn + nt*16 + col16;
        if (j < N){
#pragma unroll
          for (int rg = 0; rg < 4; rg++){
            int i = ibase + rg;
            if (i < M) Cb[(long)i*N + j] = acc[mt][nt][rg]*alpha;
          }
        }
      }
    }
  } else {
    int h = hb >> 2, b = hb & 3;
#pragma unroll
    for (int mt = 0; mt < 4; mt++){
      int ibase = i0 + wm + mt*16 + quad*4;
#pragma unroll
      for (int nt = 0; nt < 4; nt++){
        int n = j0 + wn + nt*16 + col16;
        if (n < NV){
          int d = n / 129, f = n - d*129;
          float* oc = C + ((long)(b*64 + h*16 + d)*Tt)*Ff + f;
#pragma unroll
          for (int rg = 0; rg < 4; rg++){
            int i = ibase + rg;
            if (i < M) oc[(long)i*Ff] = acc[mt][nt][rg];
          }
        }
      }
    }
  }
}

// softmax over row of 1000 f32; writes P bf16 (padded to 1024, zeros) in place
__global__ void k_softmax(float* __restrict__ S){
  float* row = S + (size_t)blockIdx.x * Tt;
  __hip_bfloat16* prow = (__hip_bfloat16*)row;
  int tid = threadIdx.x;
  __shared__ float red[4];
  float lv[4];
#pragma unroll
  for (int k = 0; k < 4; k++){ int idx = tid + k*256; lv[k] = (idx < Tt) ? row[idx] : -1e30f; }
  float m = fmaxf(fmaxf(lv[0], lv[1]), fmaxf(lv[2], lv[3]));
  m = blk_max256(m, red);
  float s = 0.f;
#pragma unroll
  for (int k = 0; k < 4; k++){ lv[k] = __expf(lv[k]-m); s += lv[k]; }
  s = blk_sum256(s, red);
  float inv = 1.f/s;
#pragma unroll
  for (int k = 0; k < 4; k++){
    int idx = tid + k*256;
    prow[idx] = __float2bfloat16(idx < Tt ? lv[k]*inv : 0.f);
  }
}

// ---------------- proj stage A: 1x1 conv 64->64 + bias + prelu, write to scratch,
// accumulate per-(b,t) sum/sumsq via segmented wave reduction + global atomics.
// Weights via wave-uniform global reads (scalar path), input column in VGPRs.
__global__ __launch_bounds__(256) void k_projA(const float* __restrict__ in, float* __restrict__ out,
    const float* __restrict__ W, const float* __restrict__ bias,
    const float* __restrict__ pa, float* __restrict__ pstat){
  int gid = blockIdx.x*256 + threadIdx.x;
  float s1 = 0.f, s2 = 0.f;
  int r = 3999;
  if (gid < Bz*TF){
    int b = gid / TF;
    int p = gid - b*TF;
    r = gid / 129;        // = b*1000 + t  (since TF = 1000*129)
    size_t base = (size_t)b*CTF + p;
    float al = pa[0];
    float v[64];
#pragma unroll
    for (int c = 0; c < 64; c++) v[c] = in[base + (size_t)c*TF];
    for (int o = 0; o < 64; o++){
      float s = bias[o];
      const float4* w4 = (const float4*)&W[o*64];
#pragma unroll
      for (int c = 0; c < 16; c++){
        float4 w = w4[c];
        s += v[4*c]*w.x + v[4*c+1]*w.y + v[4*c+2]*w.z + v[4*c+3]*w.w;
      }
      s = s >= 0.f ? s : al*s;
      out[base + (size_t)o*TF] = s;
      s1 += s; s2 += s*s;
    }
  }
  // per-(b,t) row stats; a wave (64 consecutive gids) spans at most 2 rows of 129
  int rlo = __shfl(r, 0, 64), rhi = __shfl(r, 63, 64);
  if (rlo == rhi){
    float a1 = wave_sum(s1), a2 = wave_sum(s2);
    if ((threadIdx.x & 63) == 0){
      atomicAdd(&pstat[rlo*2], a1); atomicAdd(&pstat[rlo*2+1], a2);
    }
  } else {
    bool lo = (r == rlo);
    float a1 = wave_sum(lo ? s1 : 0.f);
    float a2 = wave_sum(lo ? s2 : 0.f);
    float b1 = wave_sum(lo ? 0.f : s1);
    float b2 = wave_sum(lo ? 0.f : s2);
    if ((threadIdx.x & 63) == 0){
      atomicAdd(&pstat[rlo*2], a1); atomicAdd(&pstat[rlo*2+1], a2);
      atomicAdd(&pstat[rhi*2], b1); atomicAdd(&pstat[rhi*2+1], b2);
    }
  }
}

// ---------------- proj stage B: LN over (c,f) per (b,t) + residual, final write ----
__global__ __launch_bounds__(256) void k_projB(const float* __restrict__ proj,
    const float* __restrict__ Y, float* __restrict__ Out,
    const float* __restrict__ pstat, const float* __restrict__ lng,
    const float* __restrict__ lnb){
  int t = blockIdx.x, b = blockIdx.y;
  int r = b*1000 + t;
  const float n = 64.f*129.f;
  float mu = pstat[r*2] / n;
  float var = pstat[r*2+1] / n - mu*mu;
  float rstd = rsqrtf(var + EPSv);
  size_t base = (size_t)b*CTF + (size_t)t*Ff;
  for (int idx = threadIdx.x; idx < 64*Ff; idx += 256){
    int c = idx / Ff, f = idx - c*Ff;
    size_t off = base + (size_t)c*TF + f;
    Out[off] = (proj[off]-mu)*rstd*lng[idx] + lnb[idx] + Y[off];
  }
}

extern "C" void kernel_launch(void* const* d_in, const int* in_sizes, int n_in,
                              void* d_out, int out_size, void* d_ws, size_t ws_size,
                              hipStream_t stream){
  const float* x       = (const float*)d_in[0];
  const float* br_g    = (const float*)d_in[1];
  const float* br_b    = (const float*)d_in[2];
  const float* lisa_w  = (const float*)d_in[3];
  const float* lisa_in = (const float*)d_in[4];
  const float* lisa_ll = (const float*)d_in[5];
  const float* lisa_lh = (const float*)d_in[6];
  const float* mix_g   = (const float*)d_in[7];
  const float* mix_b   = (const float*)d_in[8];
  const float* convb_w = (const float*)d_in[9];
  const float* convb_b = (const float*)d_in[10];
  const float* gn_g    = (const float*)d_in[11];
  const float* gn_b    = (const float*)d_in[12];
  const float* convb_a = (const float*)d_in[13];
  const float* q_w  = (const float*)d_in[14];
  const float* q_b  = (const float*)d_in[15];
  const float* q_a  = (const float*)d_in[16];
  const float* q_lg = (const float*)d_in[17];
  const float* q_lb = (const float*)d_in[18];
  const float* k_w  = (const float*)d_in[19];
  const float* k_b  = (const float*)d_in[20];
  const float* k_a  = (const float*)d_in[21];
  const float* k_lg = (const float*)d_in[22];
  const float* k_lb = (const float*)d_in[23];
  const float* v_w  = (const float*)d_in[24];
  const float* v_b  = (const float*)d_in[25];
  const float* v_a  = (const float*)d_in[26];
  const float* v_lg = (const float*)d_in[27];
  const float* v_lb = (const float*)d_in[28];
  const float* p_w  = (const float*)d_in[29];
  const float* p_b  = (const float*)d_in[30];
  const float* p_a  = (const float*)d_in[31];
  const float* p_lg = (const float*)d_in[32];
  const float* p_lb = (const float*)d_in[33];

  float* out  = (float*)d_out;
  float* buf0 = (float*)d_ws;          // bsum -> Z -> Vt|S -> proj scratch
  float* buf1 = buf0 + SZ;             // ln temp -> Y ("output")
  float* buf2 = buf1 + SZ;             // lisa_h temp -> Qm|Km|Vm (bf16)
  float* chm  = buf2 + SZ;             // 6*256 channel-sum sections (one per ln4d stage)
  float* filt = chm + 1536;            // 48 (pad 64)
  float* stat = filt + 64;             // 8  (pad 16)
  float* gapv = stat + 16;             // 33024 (lisa loop only)
  float* pstat = gapv;                 // 8000 -- ALIASES gapv (dead after lisa loop);
                                       // zeroed by k_zerop right before k_projA

  if (ws_size < (3*(size_t)SZ + 40000)*sizeof(float)) return;

  __hip_bfloat16* Qm = (__hip_bfloat16*)buf2;                 // 16*1000*544
  __hip_bfloat16* Km = Qm + (size_t)16*Tt*KQK;                // 16*1000*544
  __hip_bfloat16* Vm = Km + (size_t)16*Tt*KQK;                // 16*1000*2064
  __hip_bfloat16* Z  = (__hip_bfloat16*)buf0;                 // 4*96*129000 bf16 (99 MB)
  ushort* Vt = (ushort*)buf0;                                 // 16*2064*1024 bf16 (after Z dead)
  float*  S  = buf0 + (size_t)16*NV*KPV/2;                    // 16*1000*1000 f32

  k_zeroinit<<<8, 256, 0, stream>>>(stat, chm);

  const int dils[3] = {3, 5, 7};
  for (int i = 0; i < 3; i++){
    k_ln4d<<<2016, 256, 0, stream>>>(x, buf1, br_g + i*64, br_b + i*64, chm + i*256);
    k_filt<<<1, 64, 0, stream>>>(chm + i*256, lisa_w + i*768, filt);
    k_lisa_h<<<Bz*Cc*Tt, 64, 0, stream>>>(buf1, buf2, filt, lisa_in + i*64, lisa_ll + i*64, lisa_lh + i*64, dils[i]);
    k_ln4d<<<2016, 256, 0, stream>>>(buf2, buf1, br_g + (i+3)*64, br_b + (i+3)*64, chm + (3+i)*256);
    k_filt<<<1, 64, 0, stream>>>(chm + (3+i)*256, lisa_w + (i+3)*768, filt);
    k_colmean<<<dim3(3, 64, 4), 256, 0, stream>>>(buf1, gapv);
    k_lisa_v<<<dim3(30, 64, 4), 256, 0, stream>>>(buf1, x, buf0, filt, gapv,
        lisa_in + (i+3)*64, lisa_ll + (i+3)*64, lisa_lh + (i+3)*64,
        mix_g + i*64, mix_b + i*64, dils[i], i > 0 ? 1 : 0);
  }
  k_convb<<<2016, 256, 0, stream>>>(buf0, buf1, convb_w, convb_b, stat);
  k_gnapply<<<32250, 256, 0, stream>>>(buf1, gn_g, gn_b, convb_a, stat);
  k_qkvP<<<2016, 256, 0, stream>>>(buf1, q_w, q_b, q_a, k_w, k_b, k_a, v_w, v_b, v_a, Z);
  k_qkvN<<<dim3(1000, 4), 256, 0, stream>>>(Z, q_lg, q_lb, k_lg, k_lb, v_lg, v_lb, Qm, Km, Vm);
  k_vt<<<dim3(16, 33, 16), 256, 0, stream>>>((const ushort*)Vm, Vt);
  k_gemm<0><<<dim3(8, 8, 16), 256, 0, stream>>>(
      (const ushort*)Qm, KQK, (long)Tt*KQK,
      (const ushort*)Km, KQK, (long)Tt*KQK,
      S, (long)Tt*Tt, Tt, Tt, KQK, 0.04402254531f);
  k_softmax<<<16000, 256, 0, stream>>>(S);
  k_gemm<1><<<dim3(17, 8, 16), 256, 0, stream>>>(
      (const ushort*)S, LDP, (long)Tt*LDP,
      Vt, KPV, (long)NV*KPV,
      out, 0, Tt, NV, KPV, 1.f);
  // proj: conv+prelu+stats into buf0 (free after attention), then LN+residual into out
  k_zerop<<<32, 256, 0, stream>>>(pstat);
  k_projA<<<2016, 256, 0, stream>>>(out, buf0, p_w, p_b, p_a, pstat);
  k_projB<<<dim3(1000, 4), 256, 0, stream>>>(buf0, buf1, out, pstat, p_lg, p_lb);
}

// Round 6
// 2906.102 us; speedup vs baseline: 3.7870x; 1.4812x over previous
//
#include <hip/hip_runtime.h>
#include <hip/hip_bf16.h>

#define Bz 4
#define Cc 64
#define Tt 1000
#define Ff 129
#define TF 129000            // Tt*Ff
#define CTF 8256000          // Cc*TF
#define SZ 33024000L         // Bz*CTF
#define EPSv 1e-5f

#define KQK 544              // 516 padded to mult of 32
#define KPV 1024             // 1000 padded
#define LDP 2000             // P row stride in bf16 (= 1000 f32 reused in place)
#define NV 2064              // 16*129

typedef __attribute__((ext_vector_type(8))) short bf16x8;
typedef __attribute__((ext_vector_type(4))) float f32x4;

// bf16 <-> bits helpers (no .data member on this ROCm's __hip_bfloat16)
__device__ __forceinline__ ushort bf_bits(__hip_bfloat16 h){
  union { __hip_bfloat16 h; ushort u; } c; c.h = h; return c.u;
}
__device__ __forceinline__ float bits_f32(ushort u){
  union { float f; unsigned int i; } c; c.i = ((unsigned int)u) << 16; return c.f;
}

// ---------------- reduction helpers ----------------
__device__ __forceinline__ float wave_sum(float v){
#pragma unroll
  for (int o = 32; o; o >>= 1) v += __shfl_down(v, o, 64);
  return v;
}
__device__ __forceinline__ float wave_bcast_sum(float v){
#pragma unroll
  for (int o = 1; o < 64; o <<= 1) v += __shfl_xor(v, o, 64);
  return v;
}
__device__ __forceinline__ float blk_sum256(float v, float* red){
  __syncthreads();
  v = wave_sum(v);
  int tid = threadIdx.x;
  if ((tid & 63) == 0) red[tid >> 6] = v;
  __syncthreads();
  return red[0] + red[1] + red[2] + red[3];
}
__device__ __forceinline__ float blk_max256(float v, float* red){
  __syncthreads();
#pragma unroll
  for (int o = 32; o; o >>= 1) v = fmaxf(v, __shfl_down(v, o, 64));
  int tid = threadIdx.x;
  if ((tid & 63) == 0) red[tid >> 6] = v;
  __syncthreads();
  return fmaxf(fmaxf(red[0], red[1]), fmaxf(red[2], red[3]));
}

// ---------------- misc ----------------
__global__ void k_zero8(float* s){ if (threadIdx.x < 8) s[threadIdx.x] = 0.f; }
// zero pstat[8000] (aliases gapv; must run AFTER the lisa loop, before k_projA)
__global__ void k_zerop(float* ps){
  int i = blockIdx.x*256 + threadIdx.x;
  if (i < 8000) ps[i] = 0.f;
}

// ln4d: LN over channel axis per (b,t,f); std = sqrt(max(var, EPS))
// ROUND-3 PROVEN FORM -- do not add epilogue loops over v[]: any loop the
// early pipeline sees as runtime-indexed (atomics/shfl in body) blocks SROA
// promotion and sends the WHOLE array to scratch (r4: 1565us, r5: 418us,
// both VGPR=76, VALUBusy <4%). Straight-line + early return keeps it in VGPRs.
__global__ __launch_bounds__(256) void k_ln4d(const float* __restrict__ in, float* __restrict__ out,
                       const float* __restrict__ g, const float* __restrict__ be){
  int gid = blockIdx.x*256 + threadIdx.x;
  if (gid >= Bz*TF) return;
  int b = gid / TF, p = gid - b*TF;
  size_t base = (size_t)b*CTF + p;
  float v[64]; float s1 = 0.f, s2 = 0.f;
#pragma unroll
  for (int c = 0; c < 64; c++){ float x = in[base + (size_t)c*TF]; v[c] = x; s1 += x; s2 += x*x; }
  float mu = s1*(1.f/64.f);
  float var = s2*(1.f/64.f) - mu*mu;
  float rstd = rsqrtf(fmaxf(var, EPSv));
#pragma unroll
  for (int c = 0; c < 64; c++) out[base + (size_t)c*TF] = (v[c]-mu)*rstd*g[c] + be[c];
}

// per-(b,c) mean over (t,f)
__global__ void k_chmean(const float* __restrict__ in, float* __restrict__ m){
  int bc = blockIdx.x;
  const float4* p = (const float4*)(in + (size_t)bc*TF);
  float s = 0.f;
  for (int i = threadIdx.x; i < TF/4; i += 256){ float4 u = p[i]; s += u.x+u.y+u.z+u.w; }
  __shared__ float red[4];
  s = blk_sum256(s, red);
  if (threadIdx.x == 0) m[bc] = s * (1.f/(float)TF);
}

__global__ void k_filt(const float* __restrict__ m, const float* __restrict__ w, float* __restrict__ filt){
  int t = threadIdx.x;
  if (t >= Bz*12) return;
  int b = t/12, gk = t - b*12;
  float s = 0.f;
  for (int c = 0; c < 64; c++) s += m[b*64+c]*w[gk*64+c];
  filt[t] = tanhf(s);
}

// lisa horizontal: one wave per (b,c,t) row of 129
__global__ void k_lisa_h(const float* __restrict__ in, float* __restrict__ out,
                         const float* __restrict__ filt, const float* __restrict__ iap,
                         const float* __restrict__ llp, const float* __restrict__ lhp, int dil){
  __shared__ float r[132];
  int row = blockIdx.x;
  int c = (row / Tt) % Cc;
  int b = row / (Tt*Cc);
  size_t base = (size_t)row * Ff;
  int lane = threadIdx.x;
  float s = 0.f;
  for (int f = lane; f < Ff; f += 64){ float x = in[base+f]; r[f] = x; s += x; }
  s = wave_bcast_sum(s);
  float gap = s * (1.f/129.f);
  __syncthreads();
  int g3 = b*12 + (c>>4)*3;
  float w0 = filt[g3], w1 = filt[g3+1], w2 = filt[g3+2];
  float ia = iap[c], ll = llp[c], lh1 = lhp[c] + 1.f, ia1 = ia + 1.f;
  for (int f = lane; f < Ff; f += 64){
    int fm = f - dil; fm = fm < 0 ? -fm : fm;
    int fp = f + dil; fp = fp > 128 ? 256 - fp : fp;
    float conv = w0*r[fm] + w1*r[f] + w2*r[fp];
    out[base+f] = (conv*ia1 - ia*gap)*ll + r[f]*lh1;
  }
}

// column means over t per (b,c,f)
__global__ void k_colmean(const float* __restrict__ in, float* __restrict__ gapv){
  int lane = threadIdx.x & 63, strip = threadIdx.x >> 6;
  int f = blockIdx.x*64 + lane;
  int c = blockIdx.y, b = blockIdx.z;
  size_t cb = ((size_t)(b*Cc + c))*TF + f;
  float s = 0.f;
  if (f < Ff){ for (int t = strip; t < Tt; t += 4) s += in[cb + (size_t)t*Ff]; }
  __shared__ float sm[256];
  sm[threadIdx.x] = s; __syncthreads();
  if (strip == 0 && f < Ff){
    float tot = sm[threadIdx.x] + sm[threadIdx.x+64] + sm[threadIdx.x+128] + sm[threadIdx.x+192];
    gapv[(b*Cc + c)*Ff + f] = tot * (1.f/(float)Tt);
  }
}

// lisa vertical fused with bsum accumulate
__global__ void k_lisa_v(const float* __restrict__ in, const float* __restrict__ x,
                         float* __restrict__ A, const float* __restrict__ filt,
                         const float* __restrict__ gapv,
                         const float* __restrict__ iap, const float* __restrict__ llp,
                         const float* __restrict__ lhp,
                         const float* __restrict__ mgp, const float* __restrict__ mbp,
                         int dil, int accum){
  int lane = threadIdx.x & 63, strip = threadIdx.x >> 6;
  int ftile = blockIdx.x % 3, tch = blockIdx.x / 3;
  int f = ftile*64 + lane;
  if (f >= Ff) return;
  int c = blockIdx.y, b = blockIdx.z;
  int g3 = b*12 + (c>>4)*3;
  float w0 = filt[g3], w1 = filt[g3+1], w2 = filt[g3+2];
  float ia = iap[c], ll = llp[c], lh1 = lhp[c]+1.f, ia1 = ia+1.f;
  float mg = mgp[c], mb = mbp[c];
  float gap = gapv[(b*Cc+c)*Ff + f];
  size_t cb = ((size_t)(b*Cc + c))*TF + f;
  int tend = tch*100 + 100;
  for (int t = tch*100 + strip; t < tend; t += 4){
    int tm = t - dil; tm = tm < 0 ? -tm : tm;
    int tp = t + dil; tp = tp > 999 ? 1998 - tp : tp;
    float vm = in[cb + (size_t)tm*Ff];
    float vc = in[cb + (size_t)t*Ff];
    float vp = in[cb + (size_t)tp*Ff];
    float conv = w0*vm + w1*vc + w2*vp;
    float val = (conv*ia1 - ia*gap)*ll + vc*lh1;
    float o = mg*val + mb*x[cb + (size_t)t*Ff];
    size_t oi = cb + (size_t)t*Ff;
    A[oi] = accum ? (A[oi] + o) : o;
  }
}

// 1x1 conv 64->64, fused with per-batch global stats (sum, sumsq) for the
// following GroupNorm. stat must be zeroed before this launch.
// Weights read directly from global with wave-uniform addresses (scalar-load path).
__global__ __launch_bounds__(256) void k_convb(const float* __restrict__ in, float* __restrict__ out,
                        const float* __restrict__ W, const float* __restrict__ bias,
                        float* __restrict__ stat){
  __shared__ float bacc[8];
  if (threadIdx.x < 8) bacc[threadIdx.x] = 0.f;
  __syncthreads();
  int gid = blockIdx.x*256 + threadIdx.x;
  float s1 = 0.f, s2 = 0.f;
  int b = 0;
  if (gid < Bz*TF){
    b = gid / TF;
    int p = gid - b*TF;
    size_t base = (size_t)b*CTF + p;
    float v[64];
#pragma unroll
    for (int c = 0; c < 64; c++) v[c] = in[base + (size_t)c*TF];
    for (int o = 0; o < 64; o++){
      float s = bias[o];
      const float4* w4 = (const float4*)&W[o*64];
#pragma unroll
      for (int c = 0; c < 16; c++){
        float4 w = w4[c];
        s += v[4*c]*w.x + v[4*c+1]*w.y + v[4*c+2]*w.z + v[4*c+3]*w.w;
      }
      out[base + (size_t)o*TF] = s;
      s1 += s; s2 += s*s;
    }
  }
  // reduce: wave fast-path when the whole wave shares one batch index
  int blo = __shfl(b, 0, 64), bhi = __shfl(b, 63, 64);
  if (blo == bhi){
    float w1 = wave_sum(s1), w2 = wave_sum(s2);
    if ((threadIdx.x & 63) == 0){ atomicAdd(&bacc[blo*2], w1); atomicAdd(&bacc[blo*2+1], w2); }
  } else {
    atomicAdd(&bacc[b*2], s1); atomicAdd(&bacc[b*2+1], s2);
  }
  __syncthreads();
  if (threadIdx.x < 8 && bacc[threadIdx.x] != 0.f) atomicAdd(&stat[threadIdx.x], bacc[threadIdx.x]);
}

// ---------------- QKV projection, stage P: Z[b][r=0..95][p] = prelu(W y + b), bf16 ----
// rows 0-15: Q(h*4+e), 16-31: K, 32-95: V(h*16+d)
// GroupNorm+prelu of the conv output is applied INLINE here (k_gnapply pass
// removed): v[c] = prelu((y-mu)*rstd*gn_g[c]+gn_b[c]).  Weights/bias/alpha via
// wave-uniform global reads (scalar path) -- no LDS.
__global__ __launch_bounds__(256) void k_qkvP(const float* __restrict__ Y,
    const float* __restrict__ gng, const float* __restrict__ gnb,
    const float* __restrict__ gna, const float* __restrict__ stat,
    const float* __restrict__ qw, const float* __restrict__ qb, const float* __restrict__ qa,
    const float* __restrict__ kw, const float* __restrict__ kb, const float* __restrict__ ka,
    const float* __restrict__ vw, const float* __restrict__ vb, const float* __restrict__ va,
    __hip_bfloat16* __restrict__ Z){
  int gid = blockIdx.x*256 + threadIdx.x;
  if (gid >= Bz*TF) return;
  int b = gid / TF, p = gid - b*TF;
  size_t base = (size_t)b*CTF + p;
  float gmu = stat[b*2] * (1.f/(float)CTF);
  float gvar = stat[b*2+1] * (1.f/(float)CTF) - gmu*gmu;
  float grs = rsqrtf(gvar + EPSv);
  float gal = gna[0];
  float v[64];
#pragma unroll
  for (int c = 0; c < 64; c++){
    float z = (Y[base + (size_t)c*TF] - gmu)*grs*gng[c] + gnb[c];
    v[c] = z >= 0.f ? z : gal*z;
  }
  __hip_bfloat16* zb = Z + ((size_t)b*96)*TF + p;
  // Q: rows 0-15
  for (int r = 0; r < 16; r++){
    float s = qb[r];
    const float4* w4 = (const float4*)&qw[r*64];
#pragma unroll
    for (int c = 0; c < 16; c++){
      float4 w = w4[c];
      s += v[4*c]*w.x + v[4*c+1]*w.y + v[4*c+2]*w.z + v[4*c+3]*w.w;
    }
    float al = qa[r>>2];
    s = s >= 0.f ? s : al*s;
    zb[(size_t)r*TF] = __float2bfloat16(s);
  }
  // K: rows 16-31
  for (int r = 0; r < 16; r++){
    float s = kb[r];
    const float4* w4 = (const float4*)&kw[r*64];
#pragma unroll
    for (int c = 0; c < 16; c++){
      float4 w = w4[c];
      s += v[4*c]*w.x + v[4*c+1]*w.y + v[4*c+2]*w.z + v[4*c+3]*w.w;
    }
    float al = ka[r>>2];
    s = s >= 0.f ? s : al*s;
    zb[(size_t)(16+r)*TF] = __float2bfloat16(s);
  }
  // V: rows 32-95
  for (int r = 0; r < 64; r++){
    float s = vb[r];
    const float4* w4 = (const float4*)&vw[r*64];
#pragma unroll
    for (int c = 0; c < 16; c++){
      float4 w = w4[c];
      s += v[4*c]*w.x + v[4*c+1]*w.y + v[4*c+2]*w.z + v[4*c+3]*w.w;
    }
    float al = va[r>>4];
    s = s >= 0.f ? s : al*s;
    zb[(size_t)(32+r)*TF] = __float2bfloat16(s);
  }
}

// ---------------- QKV stage N: per-(b,t) LN over (e,f) per (h,kind), write Qm/Km/Vm ----
__global__ __launch_bounds__(256) void k_qkvN(const __hip_bfloat16* __restrict__ Z,
    const float* __restrict__ qg, const float* __restrict__ qz,
    const float* __restrict__ kg, const float* __restrict__ kz,
    const float* __restrict__ vg, const float* __restrict__ vz,
    __hip_bfloat16* __restrict__ Qm, __hip_bfloat16* __restrict__ Km,
    __hip_bfloat16* __restrict__ Vm){
  __shared__ ushort zt[96*129];
  __shared__ float ps1[256], ps2[256];
  __shared__ float mug[12], rsg[12];
  int t = blockIdx.x, b = blockIdx.y;
  const ushort* Zb = (const ushort*)(Z + ((size_t)b*96)*TF + (size_t)t*Ff);
  int tid = threadIdx.x;
  // unit decomposition: 24 units of 516 items; 10 threads per unit (240 active)
  int u = tid/10, l = tid - u*10;
  int kind = 0, h = 0, jbase = 0, g = 0, rbase = 0;
  bool act = tid < 240;
  if (act){
    if (u < 4){ kind = 0; h = u; jbase = 0; g = h; rbase = h*4; }
    else if (u < 8){ kind = 1; h = u-4; jbase = 0; g = 4+h; rbase = 16+h*4; }
    else { int uv = u-8; kind = 2; h = uv>>2; jbase = (uv&3)*516; g = 8+h; rbase = 32+h*16; }
  }
  float s1 = 0.f, s2 = 0.f;
  if (act){
    for (int j = jbase + l; j < jbase + 516; j += 10){
      int e = j/129, f = j - e*129;
      int r = rbase + e;
      ushort raw = Zb[(size_t)r*TF + f];
      float z = bits_f32(raw);
      s1 += z; s2 += z*z;
      zt[r*129 + f] = raw;
    }
  }
  ps1[tid] = s1; ps2[tid] = s2;
  __syncthreads();
  if (tid < 12){
    int t0, cnt; float n;
    if (tid < 8){ t0 = tid*10; cnt = 10; n = 516.f; }
    else { t0 = (8 + (tid-8)*4)*10; cnt = 40; n = 2064.f; }
    float a = 0.f, q = 0.f;
    for (int i = 0; i < cnt; i++){ a += ps1[t0+i]; q += ps2[t0+i]; }
    float mu = a/n;
    mug[tid] = mu;
    rsg[tid] = rsqrtf(q/n - mu*mu + EPSv);
  }
  __syncthreads();
  if (act){
    float mu = mug[g], rs = rsg[g];
    size_t obase = (size_t)(h*Bz + b)*Tt + t;
    const float* lg; const float* lb; __hip_bfloat16* outp;
    if (kind == 0){ lg = qg + h*516; lb = qz + h*516; outp = Qm + obase*KQK; }
    else if (kind == 1){ lg = kg + h*516; lb = kz + h*516; outp = Km + obase*KQK; }
    else { lg = vg + h*2064; lb = vz + h*2064; outp = Vm + obase*NV; }
    for (int j = jbase + l; j < jbase + 516; j += 10){
      int e = j/129, f = j - e*129;
      int r = rbase + e;
      float z = bits_f32(zt[r*129 + f]);
      float val = (z - mu)*rs*lg[j] + lb[j];
      outp[j] = __float2bfloat16(val);
    }
  } else {
    // pad K-dim 516->544 with zeros for Q and K rows (224 pads, 14 per thread)
    int i0 = (tid - 240)*14;
    for (int i = i0; i < i0 + 14; i++){
      int kk = i/112, pj = i - kk*112;
      int hh = pj/28, off = 516 + (pj - hh*28);
      size_t obase = (size_t)(hh*Bz + b)*Tt + t;
      (kk ? Km : Qm)[obase*KQK + off] = __float2bfloat16(0.f);
    }
  }
}

// transpose V: Vm[hb][t][n] -> Vt[hb][n][tp] with tp-stride KPV, zero pad t>=1000
__global__ void k_vt(const ushort* __restrict__ Vm, ushort* __restrict__ Vt){
  __shared__ ushort tile[64][72];
  int t0 = blockIdx.x*64, n0 = blockIdx.y*64, hb = blockIdx.z;
  const ushort* src = Vm + (size_t)hb*Tt*NV;
  ushort* dst = Vt + (size_t)hb*NV*KPV;
  int nl = threadIdx.x & 63, tl = threadIdx.x >> 6;
#pragma unroll
  for (int i = 0; i < 16; i++){
    int t = tl + i*4;
    int gt = t0 + t, gn = n0 + nl;
    ushort v = 0;
    if (gt < Tt && gn < NV) v = src[(size_t)gt*NV + gn];
    tile[t][nl] = v;
  }
  __syncthreads();
  int tl2 = threadIdx.x & 63, nl2 = threadIdx.x >> 6;
#pragma unroll
  for (int i = 0; i < 16; i++){
    int n = nl2 + i*4;
    int gn = n0 + n;
    if (gn < NV) dst[(size_t)gn*KPV + t0 + tl2] = tile[tl2][n];
  }
}

// ---------------- bf16 MFMA GEMM: C[M,N] = A[M,Kc] * B^T[N,Kc]  ----------------
template<int MODE>
__global__ __launch_bounds__(256) void k_gemm(
    const ushort* __restrict__ A, int lda, long strideA,
    const ushort* __restrict__ Bt, int ldb, long strideB,
    float* __restrict__ C, long strideC,
    int M, int N, int Kc, float alpha){
  __shared__ ushort As[128*40];
  __shared__ ushort Bs[128*40];
  int hb = blockIdx.z;
  const ushort* Ab = A + (long)hb*strideA;
  const ushort* Bb = Bt + (long)hb*strideB;
  int i0 = blockIdx.y*128, j0 = blockIdx.x*128;
  int tid = threadIdx.x;
  int wave = tid >> 6, lane = tid & 63;
  int wm = (wave >> 1)*64, wn = (wave & 1)*64;
  int col16 = lane & 15, quad = lane >> 4;
  f32x4 acc[4][4] = {};
  int srow = tid >> 2;
  int scol = (tid & 3)*8;
  for (int k0 = 0; k0 < Kc; k0 += 32){
#pragma unroll
    for (int r = 0; r < 2; r++){
      int row = srow + r*64;
      int gi = i0 + row;
      float4 va = (gi < M) ? *(const float4*)(Ab + (long)gi*lda + k0 + scol)
                           : make_float4(0.f,0.f,0.f,0.f);
      *(float4*)&As[row*40 + scol] = va;
      int gj = j0 + row;
      float4 vb = (gj < N) ? *(const float4*)(Bb + (long)gj*ldb + k0 + scol)
                           : make_float4(0.f,0.f,0.f,0.f);
      *(float4*)&Bs[row*40 + scol] = vb;
    }
    __syncthreads();
    bf16x8 af[4], bfr[4];
#pragma unroll
    for (int mt = 0; mt < 4; mt++) af[mt]  = *(const bf16x8*)&As[(wm + mt*16 + col16)*40 + quad*8];
#pragma unroll
    for (int nt = 0; nt < 4; nt++) bfr[nt] = *(const bf16x8*)&Bs[(wn + nt*16 + col16)*40 + quad*8];
#pragma unroll
    for (int mt = 0; mt < 4; mt++)
#pragma unroll
      for (int nt = 0; nt < 4; nt++)
        acc[mt][nt] = __builtin_amdgcn_mfma_f32_16x16x32_bf16(af[mt], bfr[nt], acc[mt][nt], 0, 0, 0);
    __syncthreads();
  }
  if (MODE == 0){
    float* Cb = C + (long)hb*strideC;
#pragma unroll
    for (int mt = 0; mt < 4; mt++){
      int ibase = i0 + wm + mt*16 + quad*4;
#pragma unroll
      for (int nt = 0; nt < 4; nt++){
        int j = j0 + wn + nt*16 + col16;
        if (j < N){
#pragma unroll
          for (int rg = 0; rg < 4; rg++){
            int i = ibase + rg;
            if (i < M) Cb[(long)i*N + j] = acc[mt][nt][rg]*alpha;
          }
        }
      }
    }
  } else {
    int h = hb >> 2, b = hb & 3;
#pragma unroll
    for (int mt = 0; mt < 4; mt++){
      int ibase = i0 + wm + mt*16 + quad*4;
#pragma unroll
      for (int nt = 0; nt < 4; nt++){
        int n = j0 + wn + nt*16 + col16;
        if (n < NV){
          int d = n / 129, f = n - d*129;
          float* oc = C + ((long)(b*64 + h*16 + d)*Tt)*Ff + f;
#pragma unroll
          for (int rg = 0; rg < 4; rg++){
            int i = ibase + rg;
            if (i < M) oc[(long)i*Ff] = acc[mt][nt][rg];
          }
        }
      }
    }
  }
}

// softmax over row of 1000 f32; writes P bf16 (padded to 1024, zeros) in place
__global__ void k_softmax(float* __restrict__ S){
  float* row = S + (size_t)blockIdx.x * Tt;
  __hip_bfloat16* prow = (__hip_bfloat16*)row;
  int tid = threadIdx.x;
  __shared__ float red[4];
  float lv[4];
#pragma unroll
  for (int k = 0; k < 4; k++){ int idx = tid + k*256; lv[k] = (idx < Tt) ? row[idx] : -1e30f; }
  float m = fmaxf(fmaxf(lv[0], lv[1]), fmaxf(lv[2], lv[3]));
  m = blk_max256(m, red);
  float s = 0.f;
#pragma unroll
  for (int k = 0; k < 4; k++){ lv[k] = __expf(lv[k]-m); s += lv[k]; }
  s = blk_sum256(s, red);
  float inv = 1.f/s;
#pragma unroll
  for (int k = 0; k < 4; k++){
    int idx = tid + k*256;
    prow[idx] = __float2bfloat16(idx < Tt ? lv[k]*inv : 0.f);
  }
}

// ---------------- proj stage A: 1x1 conv 64->64 + bias + prelu, write to scratch,
// accumulate per-(b,t) sum/sumsq via segmented wave reduction + global atomics.
// Weights via wave-uniform global reads (scalar path), input column in VGPRs.
__global__ __launch_bounds__(256) void k_projA(const float* __restrict__ in, float* __restrict__ out,
    const float* __restrict__ W, const float* __restrict__ bias,
    const float* __restrict__ pa, float* __restrict__ pstat){
  int gid = blockIdx.x*256 + threadIdx.x;
  float s1 = 0.f, s2 = 0.f;
  int r = 3999;
  if (gid < Bz*TF){
    int b = gid / TF;
    int p = gid - b*TF;
    r = gid / 129;        // = b*1000 + t  (since TF = 1000*129)
    size_t base = (size_t)b*CTF + p;
    float al = pa[0];
    float v[64];
#pragma unroll
    for (int c = 0; c < 64; c++) v[c] = in[base + (size_t)c*TF];
    for (int o = 0; o < 64; o++){
      float s = bias[o];
      const float4* w4 = (const float4*)&W[o*64];
#pragma unroll
      for (int c = 0; c < 16; c++){
        float4 w = w4[c];
        s += v[4*c]*w.x + v[4*c+1]*w.y + v[4*c+2]*w.z + v[4*c+3]*w.w;
      }
      s = s >= 0.f ? s : al*s;
      out[base + (size_t)o*TF] = s;
      s1 += s; s2 += s*s;
    }
  }
  // per-(b,t) row stats; a wave (64 consecutive gids) spans at most 2 rows of 129
  int rlo = __shfl(r, 0, 64), rhi = __shfl(r, 63, 64);
  if (rlo == rhi){
    float a1 = wave_sum(s1), a2 = wave_sum(s2);
    if ((threadIdx.x & 63) == 0){
      atomicAdd(&pstat[rlo*2], a1); atomicAdd(&pstat[rlo*2+1], a2);
    }
  } else {
    bool lo = (r == rlo);
    float a1 = wave_sum(lo ? s1 : 0.f);
    float a2 = wave_sum(lo ? s2 : 0.f);
    float b1 = wave_sum(lo ? 0.f : s1);
    float b2 = wave_sum(lo ? 0.f : s2);
    if ((threadIdx.x & 63) == 0){
      atomicAdd(&pstat[rlo*2], a1); atomicAdd(&pstat[rlo*2+1], a2);
      atomicAdd(&pstat[rhi*2], b1); atomicAdd(&pstat[rhi*2+1], b2);
    }
  }
}

// ---------------- proj stage B: LN over (c,f) per (b,t) + residual, final write ----
// Residual Y is the RAW conv output; GN+prelu applied inline (k_gnapply removed).
__global__ __launch_bounds__(256) void k_projB(const float* __restrict__ proj,
    const float* __restrict__ Y, float* __restrict__ Out,
    const float* __restrict__ pstat, const float* __restrict__ lng,
    const float* __restrict__ lnb,
    const float* __restrict__ gng, const float* __restrict__ gnb,
    const float* __restrict__ gna, const float* __restrict__ stat){
  int t = blockIdx.x, b = blockIdx.y;
  int r = b*1000 + t;
  const float n = 64.f*129.f;
  float mu = pstat[r*2] / n;
  float var = pstat[r*2+1] / n - mu*mu;
  float rstd = rsqrtf(var + EPSv);
  float gmu = stat[b*2] * (1.f/(float)CTF);
  float gvar = stat[b*2+1] * (1.f/(float)CTF) - gmu*gmu;
  float grs = rsqrtf(gvar + EPSv);
  float gal = gna[0];
  size_t base = (size_t)b*CTF + (size_t)t*Ff;
  for (int idx = threadIdx.x; idx < 64*Ff; idx += 256){
    int c = idx / Ff, f = idx - c*Ff;
    size_t off = base + (size_t)c*TF + f;
    float y = (Y[off] - gmu)*grs*gng[c] + gnb[c];
    y = y >= 0.f ? y : gal*y;
    Out[off] = (proj[off]-mu)*rstd*lng[idx] + lnb[idx] + y;
  }
}

extern "C" void kernel_launch(void* const* d_in, const int* in_sizes, int n_in,
                              void* d_out, int out_size, void* d_ws, size_t ws_size,
                              hipStream_t stream){
  const float* x       = (const float*)d_in[0];
  const float* br_g    = (const float*)d_in[1];
  const float* br_b    = (const float*)d_in[2];
  const float* lisa_w  = (const float*)d_in[3];
  const float* lisa_in = (const float*)d_in[4];
  const float* lisa_ll = (const float*)d_in[5];
  const float* lisa_lh = (const float*)d_in[6];
  const float* mix_g   = (const float*)d_in[7];
  const float* mix_b   = (const float*)d_in[8];
  const float* convb_w = (const float*)d_in[9];
  const float* convb_b = (const float*)d_in[10];
  const float* gn_g    = (const float*)d_in[11];
  const float* gn_b    = (const float*)d_in[12];
  const float* convb_a = (const float*)d_in[13];
  const float* q_w  = (const float*)d_in[14];
  const float* q_b  = (const float*)d_in[15];
  const float* q_a  = (const float*)d_in[16];
  const float* q_lg = (const float*)d_in[17];
  const float* q_lb = (const float*)d_in[18];
  const float* k_w  = (const float*)d_in[19];
  const float* k_b  = (const float*)d_in[20];
  const float* k_a  = (const float*)d_in[21];
  const float* k_lg = (const float*)d_in[22];
  const float* k_lb = (const float*)d_in[23];
  const float* v_w  = (const float*)d_in[24];
  const float* v_b  = (const float*)d_in[25];
  const float* v_a  = (const float*)d_in[26];
  const float* v_lg = (const float*)d_in[27];
  const float* v_lb = (const float*)d_in[28];
  const float* p_w  = (const float*)d_in[29];
  const float* p_b  = (const float*)d_in[30];
  const float* p_a  = (const float*)d_in[31];
  const float* p_lg = (const float*)d_in[32];
  const float* p_lb = (const float*)d_in[33];

  float* out  = (float*)d_out;
  float* buf0 = (float*)d_ws;          // bsum -> Z -> Vt|S -> proj scratch
  float* buf1 = buf0 + SZ;             // ln temp -> Y (raw conv output; GN applied inline)
  float* buf2 = buf1 + SZ;             // lisa_h temp -> Qm|Km|Vm (bf16)
  float* chm  = buf2 + SZ;             // 256
  float* filt = chm + 1536;            // 48 (pad 64)
  float* stat = filt + 64;             // 8  (pad 16)
  float* gapv = stat + 16;             // 33024 (lisa loop only)
  float* pstat = gapv;                 // 8000 -- ALIASES gapv (dead after lisa loop);
                                       // zeroed by k_zerop right before k_projA

  if (ws_size < (3*(size_t)SZ + 40000)*sizeof(float)) return;

  __hip_bfloat16* Qm = (__hip_bfloat16*)buf2;                 // 16*1000*544
  __hip_bfloat16* Km = Qm + (size_t)16*Tt*KQK;                // 16*1000*544
  __hip_bfloat16* Vm = Km + (size_t)16*Tt*KQK;                // 16*1000*2064
  __hip_bfloat16* Z  = (__hip_bfloat16*)buf0;                 // 4*96*129000 bf16 (99 MB)
  ushort* Vt = (ushort*)buf0;                                 // 16*2064*1024 bf16 (after Z dead)
  float*  S  = buf0 + (size_t)16*NV*KPV/2;                    // 16*1000*1000 f32

  k_zero8<<<1, 64, 0, stream>>>(stat);

  const int dils[3] = {3, 5, 7};
  for (int i = 0; i < 3; i++){
    k_ln4d<<<2016, 256, 0, stream>>>(x, buf1, br_g + i*64, br_b + i*64);
    k_chmean<<<256, 256, 0, stream>>>(buf1, chm);
    k_filt<<<1, 64, 0, stream>>>(chm, lisa_w + i*768, filt);
    k_lisa_h<<<Bz*Cc*Tt, 64, 0, stream>>>(buf1, buf2, filt, lisa_in + i*64, lisa_ll + i*64, lisa_lh + i*64, dils[i]);
    k_ln4d<<<2016, 256, 0, stream>>>(buf2, buf1, br_g + (i+3)*64, br_b + (i+3)*64);
    k_chmean<<<256, 256, 0, stream>>>(buf1, chm);
    k_filt<<<1, 64, 0, stream>>>(chm, lisa_w + (i+3)*768, filt);
    k_colmean<<<dim3(3, 64, 4), 256, 0, stream>>>(buf1, gapv);
    k_lisa_v<<<dim3(30, 64, 4), 256, 0, stream>>>(buf1, x, buf0, filt, gapv,
        lisa_in + (i+3)*64, lisa_ll + (i+3)*64, lisa_lh + (i+3)*64,
        mix_g + i*64, mix_b + i*64, dils[i], i > 0 ? 1 : 0);
  }
  k_convb<<<2016, 256, 0, stream>>>(buf0, buf1, convb_w, convb_b, stat);
  // NOTE: no k_gnapply -- GN+prelu fused into k_qkvP and k_projB
  k_qkvP<<<2016, 256, 0, stream>>>(buf1, gn_g, gn_b, convb_a, stat,
      q_w, q_b, q_a, k_w, k_b, k_a, v_w, v_b, v_a, Z);
  k_qkvN<<<dim3(1000, 4), 256, 0, stream>>>(Z, q_lg, q_lb, k_lg, k_lb, v_lg, v_lb, Qm, Km, Vm);
  k_vt<<<dim3(16, 33, 16), 256, 0, stream>>>((const ushort*)Vm, Vt);
  k_gemm<0><<<dim3(8, 8, 16), 256, 0, stream>>>(
      (const ushort*)Qm, KQK, (long)Tt*KQK,
      (const ushort*)Km, KQK, (long)Tt*KQK,
      S, (long)Tt*Tt, Tt, Tt, KQK, 0.04402254531f);
  k_softmax<<<16000, 256, 0, stream>>>(S);
  k_gemm<1><<<dim3(17, 8, 16), 256, 0, stream>>>(
      (const ushort*)S, LDP, (long)Tt*LDP,
      Vt, KPV, (long)NV*KPV,
      out, 0, Tt, NV, KPV, 1.f);
  // proj: conv+prelu+stats into buf0 (free after attention), then LN+residual into out
  k_zerop<<<32, 256, 0, stream>>>(pstat);
  k_projA<<<2016, 256, 0, stream>>>(out, buf0, p_w, p_b, p_a, pstat);
  k_projB<<<dim3(1000, 4), 256, 0, stream>>>(buf0, buf1, out, pstat, p_lg, p_lb,
      gn_g, gn_b, convb_a, stat);
}

// Round 7
// 2672.808 us; speedup vs baseline: 4.1176x; 1.0873x over previous
//
#include <hip/hip_runtime.h>
#include <hip/hip_bf16.h>

#define Bz 4
#define Cc 64
#define Tt 1000
#define Ff 129
#define TF 129000            // Tt*Ff
#define CTF 8256000          // Cc*TF
#define SZ 33024000L         // Bz*CTF
#define EPSv 1e-5f

#define KQK 544              // 516 padded to mult of 32
#define KPV 1024             // 1000 padded
#define LDP 2000             // P row stride in bf16 (= 1000 f32 reused in place)
#define NV 2064              // 16*129

typedef __attribute__((ext_vector_type(8))) short bf16x8;
typedef __attribute__((ext_vector_type(4))) float f32x4;

// bf16 <-> bits helpers (no .data member on this ROCm's __hip_bfloat16)
__device__ __forceinline__ ushort bf_bits(__hip_bfloat16 h){
  union { __hip_bfloat16 h; ushort u; } c; c.h = h; return c.u;
}
__device__ __forceinline__ float bits_f32(ushort u){
  union { float f; unsigned int i; } c; c.i = ((unsigned int)u) << 16; return c.f;
}

// ---------------- reduction helpers ----------------
__device__ __forceinline__ float wave_sum(float v){
#pragma unroll
  for (int o = 32; o; o >>= 1) v += __shfl_down(v, o, 64);
  return v;
}
__device__ __forceinline__ float wave_bcast_sum(float v){
#pragma unroll
  for (int o = 1; o < 64; o <<= 1) v += __shfl_xor(v, o, 64);
  return v;
}
__device__ __forceinline__ float blk_sum256(float v, float* red){
  __syncthreads();
  v = wave_sum(v);
  int tid = threadIdx.x;
  if ((tid & 63) == 0) red[tid >> 6] = v;
  __syncthreads();
  return red[0] + red[1] + red[2] + red[3];
}
__device__ __forceinline__ float blk_max256(float v, float* red){
  __syncthreads();
#pragma unroll
  for (int o = 32; o; o >>= 1) v = fmaxf(v, __shfl_down(v, o, 64));
  int tid = threadIdx.x;
  if ((tid & 63) == 0) red[tid >> 6] = v;
  __syncthreads();
  return fmaxf(fmaxf(red[0], red[1]), fmaxf(red[2], red[3]));
}

// ---------------- misc ----------------
__global__ void k_zero8(float* s){ if (threadIdx.x < 8) s[threadIdx.x] = 0.f; }
// zero pstat[8000] (aliases gapv; must run AFTER the lisa loop, before k_projA)
__global__ void k_zerop(float* ps){
  int i = blockIdx.x*256 + threadIdx.x;
  if (i < 8000) ps[i] = 0.f;
}

// ln4d: LN over channel axis per (b,t,f); std = sqrt(max(var, EPS))
// ROUND-3 PROVEN FORM -- do not add epilogue loops over v[]: any loop the
// early pipeline sees as runtime-indexed (atomics/shfl in body) blocks SROA
// promotion and sends the WHOLE array to scratch (r4: 1565us, r5: 418us,
// both VGPR=76, VALUBusy <4%). Straight-line + early return keeps it in VGPRs.
__global__ __launch_bounds__(256) void k_ln4d(const float* __restrict__ in, float* __restrict__ out,
                       const float* __restrict__ g, const float* __restrict__ be){
  int gid = blockIdx.x*256 + threadIdx.x;
  if (gid >= Bz*TF) return;
  int b = gid / TF, p = gid - b*TF;
  size_t base = (size_t)b*CTF + p;
  float v[64]; float s1 = 0.f, s2 = 0.f;
#pragma unroll
  for (int c = 0; c < 64; c++){ float x = in[base + (size_t)c*TF]; v[c] = x; s1 += x; s2 += x*x; }
  float mu = s1*(1.f/64.f);
  float var = s2*(1.f/64.f) - mu*mu;
  float rstd = rsqrtf(fmaxf(var, EPSv));
#pragma unroll
  for (int c = 0; c < 64; c++) out[base + (size_t)c*TF] = (v[c]-mu)*rstd*g[c] + be[c];
}

// per-(b,c) mean over (t,f)  (only needed before the HORIZONTAL lisa; the
// vertical stage derives it from gapv via k_chmg)
__global__ void k_chmean(const float* __restrict__ in, float* __restrict__ m){
  int bc = blockIdx.x;
  const float4* p = (const float4*)(in + (size_t)bc*TF);
  float s = 0.f;
  for (int i = threadIdx.x; i < TF/4; i += 256){ float4 u = p[i]; s += u.x+u.y+u.z+u.w; }
  __shared__ float red[4];
  s = blk_sum256(s, red);
  if (threadIdx.x == 0) m[bc] = s * (1.f/(float)TF);
}

// chm from gapv: chm[b,c] = (1/Ff) * sum_f gapv[(b*Cc+c)*Ff + f]
// (gapv is the t-mean, so this equals the full (t,f) mean -- saves a 132MB pass)
__global__ void k_chmg(const float* __restrict__ gapv, float* __restrict__ m){
  int bc = blockIdx.x;
  const float* gp = gapv + bc*Ff;
  int lane = threadIdx.x;
  float s = gp[lane] + gp[lane+64] + (lane == 0 ? gp[128] : 0.f);
  s = wave_sum(s);
  if (lane == 0) m[bc] = s * (1.f/(float)Ff);
}

__global__ void k_filt(const float* __restrict__ m, const float* __restrict__ w, float* __restrict__ filt){
  int t = threadIdx.x;
  if (t >= Bz*12) return;
  int b = t/12, gk = t - b*12;
  float s = 0.f;
  for (int c = 0; c < 64; c++) s += m[b*64+c]*w[gk*64+c];
  filt[t] = tanhf(s);
}

// lisa horizontal: one wave per (b,c,t) row of 129
__global__ void k_lisa_h(const float* __restrict__ in, float* __restrict__ out,
                         const float* __restrict__ filt, const float* __restrict__ iap,
                         const float* __restrict__ llp, const float* __restrict__ lhp, int dil){
  __shared__ float r[132];
  int row = blockIdx.x;
  int c = (row / Tt) % Cc;
  int b = row / (Tt*Cc);
  size_t base = (size_t)row * Ff;
  int lane = threadIdx.x;
  float s = 0.f;
  for (int f = lane; f < Ff; f += 64){ float x = in[base+f]; r[f] = x; s += x; }
  s = wave_bcast_sum(s);
  float gap = s * (1.f/129.f);
  __syncthreads();
  int g3 = b*12 + (c>>4)*3;
  float w0 = filt[g3], w1 = filt[g3+1], w2 = filt[g3+2];
  float ia = iap[c], ll = llp[c], lh1 = lhp[c] + 1.f, ia1 = ia + 1.f;
  for (int f = lane; f < Ff; f += 64){
    int fm = f - dil; fm = fm < 0 ? -fm : fm;
    int fp = f + dil; fp = fp > 128 ? 256 - fp : fp;
    float conv = w0*r[fm] + w1*r[f] + w2*r[fp];
    out[base+f] = (conv*ia1 - ia*gap)*ll + r[f]*lh1;
  }
}

// column means over t per (b,c,f)
__global__ void k_colmean(const float* __restrict__ in, float* __restrict__ gapv){
  int lane = threadIdx.x & 63, strip = threadIdx.x >> 6;
  int f = blockIdx.x*64 + lane;
  int c = blockIdx.y, b = blockIdx.z;
  size_t cb = ((size_t)(b*Cc + c))*TF + f;
  float s = 0.f;
  if (f < Ff){ for (int t = strip; t < Tt; t += 4) s += in[cb + (size_t)t*Ff]; }
  __shared__ float sm[256];
  sm[threadIdx.x] = s; __syncthreads();
  if (strip == 0 && f < Ff){
    float tot = sm[threadIdx.x] + sm[threadIdx.x+64] + sm[threadIdx.x+128] + sm[threadIdx.x+192];
    gapv[(b*Cc + c)*Ff + f] = tot * (1.f/(float)Tt);
  }
}

// lisa vertical fused with bsum accumulate
__global__ void k_lisa_v(const float* __restrict__ in, const float* __restrict__ x,
                         float* __restrict__ A, const float* __restrict__ filt,
                         const float* __restrict__ gapv,
                         const float* __restrict__ iap, const float* __restrict__ llp,
                         const float* __restrict__ lhp,
                         const float* __restrict__ mgp, const float* __restrict__ mbp,
                         int dil, int accum){
  int lane = threadIdx.x & 63, strip = threadIdx.x >> 6;
  int ftile = blockIdx.x % 3, tch = blockIdx.x / 3;
  int f = ftile*64 + lane;
  if (f >= Ff) return;
  int c = blockIdx.y, b = blockIdx.z;
  int g3 = b*12 + (c>>4)*3;
  float w0 = filt[g3], w1 = filt[g3+1], w2 = filt[g3+2];
  float ia = iap[c], ll = llp[c], lh1 = lhp[c]+1.f, ia1 = ia+1.f;
  float mg = mgp[c], mb = mbp[c];
  float gap = gapv[(b*Cc+c)*Ff + f];
  size_t cb = ((size_t)(b*Cc + c))*TF + f;
  int tend = tch*100 + 100;
  for (int t = tch*100 + strip; t < tend; t += 4){
    int tm = t - dil; tm = tm < 0 ? -tm : tm;
    int tp = t + dil; tp = tp > 999 ? 1998 - tp : tp;
    float vm = in[cb + (size_t)tm*Ff];
    float vc = in[cb + (size_t)t*Ff];
    float vp = in[cb + (size_t)tp*Ff];
    float conv = w0*vm + w1*vc + w2*vp;
    float val = (conv*ia1 - ia*gap)*ll + vc*lh1;
    float o = mg*val + mb*x[cb + (size_t)t*Ff];
    size_t oi = cb + (size_t)t*Ff;
    A[oi] = accum ? (A[oi] + o) : o;
  }
}

// 1x1 conv 64->64, fused with per-batch global stats (sum, sumsq) for the
// following GroupNorm. stat must be zeroed before this launch.
// Weights (16KB, fits scalar K-cache) via wave-uniform global reads.
__global__ __launch_bounds__(256) void k_convb(const float* __restrict__ in, float* __restrict__ out,
                        const float* __restrict__ W, const float* __restrict__ bias,
                        float* __restrict__ stat){
  __shared__ float bacc[8];
  if (threadIdx.x < 8) bacc[threadIdx.x] = 0.f;
  __syncthreads();
  int gid = blockIdx.x*256 + threadIdx.x;
  float s1 = 0.f, s2 = 0.f;
  int b = 0;
  if (gid < Bz*TF){
    b = gid / TF;
    int p = gid - b*TF;
    size_t base = (size_t)b*CTF + p;
    float v[64];
#pragma unroll
    for (int c = 0; c < 64; c++) v[c] = in[base + (size_t)c*TF];
    for (int o = 0; o < 64; o++){
      float s = bias[o];
      const float4* w4 = (const float4*)&W[o*64];
#pragma unroll
      for (int c = 0; c < 16; c++){
        float4 w = w4[c];
        s += v[4*c]*w.x + v[4*c+1]*w.y + v[4*c+2]*w.z + v[4*c+3]*w.w;
      }
      out[base + (size_t)o*TF] = s;
      s1 += s; s2 += s*s;
    }
  }
  // reduce: wave fast-path when the whole wave shares one batch index
  int blo = __shfl(b, 0, 64), bhi = __shfl(b, 63, 64);
  if (blo == bhi){
    float w1 = wave_sum(s1), w2 = wave_sum(s2);
    if ((threadIdx.x & 63) == 0){ atomicAdd(&bacc[blo*2], w1); atomicAdd(&bacc[blo*2+1], w2); }
  } else {
    atomicAdd(&bacc[b*2], s1); atomicAdd(&bacc[b*2+1], s2);
  }
  __syncthreads();
  if (threadIdx.x < 8 && bacc[threadIdx.x] != 0.f) atomicAdd(&stat[threadIdx.x], bacc[threadIdx.x]);
}

// ---------------- QKV projection, stage P: Z[b][r=0..95][p] = prelu(W y + b), bf16 ----
// rows 0-15: Q(h*4+e), 16-31: K, 32-95: V(h*16+d)
// GroupNorm+prelu of the conv output applied INLINE (k_gnapply pass removed).
// Weights LDS-staged: 24.5KB exceeds the ~16KB scalar K-cache, so the r6
// scalar-path version thrashed it (299us, VALUBusy 41%); LDS form ran 205us (r3).
__global__ __launch_bounds__(256) void k_qkvP(const float* __restrict__ Y,
    const float* __restrict__ gng, const float* __restrict__ gnb,
    const float* __restrict__ gna, const float* __restrict__ stat,
    const float* __restrict__ qw, const float* __restrict__ qb, const float* __restrict__ qa,
    const float* __restrict__ kw, const float* __restrict__ kb, const float* __restrict__ ka,
    const float* __restrict__ vw, const float* __restrict__ vb, const float* __restrict__ va,
    __hip_bfloat16* __restrict__ Z){
  __shared__ float Ws[96*64];
  __shared__ float Bs[96], As[96];
  for (int i = threadIdx.x; i < 96*64; i += 256){
    int r = i >> 6, c = i & 63;
    float w;
    if (r < 16) w = qw[(r)*64 + c];
    else if (r < 32) w = kw[(r-16)*64 + c];
    else w = vw[(r-32)*64 + c];
    Ws[i] = w;
  }
  if (threadIdx.x < 96){
    int r = threadIdx.x;
    if (r < 16){ Bs[r] = qb[r]; As[r] = qa[r>>2]; }
    else if (r < 32){ Bs[r] = kb[r-16]; As[r] = ka[(r-16)>>2]; }
    else { Bs[r] = vb[r-32]; As[r] = va[(r-32)>>4]; }
  }
  __syncthreads();
  int gid = blockIdx.x*256 + threadIdx.x;
  if (gid >= Bz*TF) return;
  int b = gid / TF, p = gid - b*TF;
  size_t base = (size_t)b*CTF + p;
  float gmu = stat[b*2] * (1.f/(float)CTF);
  float gvar = stat[b*2+1] * (1.f/(float)CTF) - gmu*gmu;
  float grs = rsqrtf(gvar + EPSv);
  float gal = gna[0];
  float v[64];
#pragma unroll
  for (int c = 0; c < 64; c++){
    float z = (Y[base + (size_t)c*TF] - gmu)*grs*gng[c] + gnb[c];
    v[c] = z >= 0.f ? z : gal*z;
  }
  __hip_bfloat16* zb = Z + ((size_t)b*96)*TF + p;
  for (int r = 0; r < 96; r++){
    float s = Bs[r];
    const float4* w4 = (const float4*)&Ws[r*64];
#pragma unroll
    for (int c = 0; c < 16; c++){
      float4 w = w4[c];
      s += v[4*c]*w.x + v[4*c+1]*w.y + v[4*c+2]*w.z + v[4*c+3]*w.w;
    }
    s = s >= 0.f ? s : As[r]*s;
    zb[(size_t)r*TF] = __float2bfloat16(s);
  }
}

// ---------------- QKV stage N: per-(b,t) LN over (e,f) per (h,kind), write Qm/Km/Vm ----
__global__ __launch_bounds__(256) void k_qkvN(const __hip_bfloat16* __restrict__ Z,
    const float* __restrict__ qg, const float* __restrict__ qz,
    const float* __restrict__ kg, const float* __restrict__ kz,
    const float* __restrict__ vg, const float* __restrict__ vz,
    __hip_bfloat16* __restrict__ Qm, __hip_bfloat16* __restrict__ Km,
    __hip_bfloat16* __restrict__ Vm){
  __shared__ ushort zt[96*129];
  __shared__ float ps1[256], ps2[256];
  __shared__ float mug[12], rsg[12];
  int t = blockIdx.x, b = blockIdx.y;
  const ushort* Zb = (const ushort*)(Z + ((size_t)b*96)*TF + (size_t)t*Ff);
  int tid = threadIdx.x;
  // unit decomposition: 24 units of 516 items; 10 threads per unit (240 active)
  int u = tid/10, l = tid - u*10;
  int kind = 0, h = 0, jbase = 0, g = 0, rbase = 0;
  bool act = tid < 240;
  if (act){
    if (u < 4){ kind = 0; h = u; jbase = 0; g = h; rbase = h*4; }
    else if (u < 8){ kind = 1; h = u-4; jbase = 0; g = 4+h; rbase = 16+h*4; }
    else { int uv = u-8; kind = 2; h = uv>>2; jbase = (uv&3)*516; g = 8+h; rbase = 32+h*16; }
  }
  float s1 = 0.f, s2 = 0.f;
  if (act){
    for (int j = jbase + l; j < jbase + 516; j += 10){
      int e = j/129, f = j - e*129;
      int r = rbase + e;
      ushort raw = Zb[(size_t)r*TF + f];
      float z = bits_f32(raw);
      s1 += z; s2 += z*z;
      zt[r*129 + f] = raw;
    }
  }
  ps1[tid] = s1; ps2[tid] = s2;
  __syncthreads();
  if (tid < 12){
    int t0, cnt; float n;
    if (tid < 8){ t0 = tid*10; cnt = 10; n = 516.f; }
    else { t0 = (8 + (tid-8)*4)*10; cnt = 40; n = 2064.f; }
    float a = 0.f, q = 0.f;
    for (int i = 0; i < cnt; i++){ a += ps1[t0+i]; q += ps2[t0+i]; }
    float mu = a/n;
    mug[tid] = mu;
    rsg[tid] = rsqrtf(q/n - mu*mu + EPSv);
  }
  __syncthreads();
  if (act){
    float mu = mug[g], rs = rsg[g];
    size_t obase = (size_t)(h*Bz + b)*Tt + t;
    const float* lg; const float* lb; __hip_bfloat16* outp;
    if (kind == 0){ lg = qg + h*516; lb = qz + h*516; outp = Qm + obase*KQK; }
    else if (kind == 1){ lg = kg + h*516; lb = kz + h*516; outp = Km + obase*KQK; }
    else { lg = vg + h*2064; lb = vz + h*2064; outp = Vm + obase*NV; }
    for (int j = jbase + l; j < jbase + 516; j += 10){
      int e = j/129, f = j - e*129;
      int r = rbase + e;
      float z = bits_f32(zt[r*129 + f]);
      float val = (z - mu)*rs*lg[j] + lb[j];
      outp[j] = __float2bfloat16(val);
    }
  } else {
    // pad K-dim 516->544 with zeros for Q and K rows (224 pads, 14 per thread)
    int i0 = (tid - 240)*14;
    for (int i = i0; i < i0 + 14; i++){
      int kk = i/112, pj = i - kk*112;
      int hh = pj/28, off = 516 + (pj - hh*28);
      size_t obase = (size_t)(hh*Bz + b)*Tt + t;
      (kk ? Km : Qm)[obase*KQK + off] = __float2bfloat16(0.f);
    }
  }
}

// transpose V: Vm[hb][t][n] -> Vt[hb][n][tp] with tp-stride KPV, zero pad t>=1000
__global__ void k_vt(const ushort* __restrict__ Vm, ushort* __restrict__ Vt){
  __shared__ ushort tile[64][72];
  int t0 = blockIdx.x*64, n0 = blockIdx.y*64, hb = blockIdx.z;
  const ushort* src = Vm + (size_t)hb*Tt*NV;
  ushort* dst = Vt + (size_t)hb*NV*KPV;
  int nl = threadIdx.x & 63, tl = threadIdx.x >> 6;
#pragma unroll
  for (int i = 0; i < 16; i++){
    int t = tl + i*4;
    int gt = t0 + t, gn = n0 + nl;
    ushort v = 0;
    if (gt < Tt && gn < NV) v = src[(size_t)gt*NV + gn];
    tile[t][nl] = v;
  }
  __syncthreads();
  int tl2 = threadIdx.x & 63, nl2 = threadIdx.x >> 6;
#pragma unroll
  for (int i = 0; i < 16; i++){
    int n = nl2 + i*4;
    int gn = n0 + n;
    if (gn < NV) dst[(size_t)gn*KPV + t0 + tl2] = tile[tl2][n];
  }
}

// ---------------- bf16 MFMA GEMM: C[M,N] = A[M,Kc] * B^T[N,Kc]  ----------------
template<int MODE>
__global__ __launch_bounds__(256) void k_gemm(
    const ushort* __restrict__ A, int lda, long strideA,
    const ushort* __restrict__ Bt, int ldb, long strideB,
    float* __restrict__ C, long strideC,
    int M, int N, int Kc, float alpha){
  __shared__ ushort As[128*40];
  __shared__ ushort Bs[128*40];
  int hb = blockIdx.z;
  const ushort* Ab = A + (long)hb*strideA;
  const ushort* Bb = Bt + (long)hb*strideB;
  int i0 = blockIdx.y*128, j0 = blockIdx.x*128;
  int tid = threadIdx.x;
  int wave = tid >> 6, lane = tid & 63;
  int wm = (wave >> 1)*64, wn = (wave & 1)*64;
  int col16 = lane & 15, quad = lane >> 4;
  f32x4 acc[4][4] = {};
  int srow = tid >> 2;
  int scol = (tid & 3)*8;
  for (int k0 = 0; k0 < Kc; k0 += 32){
#pragma unroll
    for (int r = 0; r < 2; r++){
      int row = srow + r*64;
      int gi = i0 + row;
      float4 va = (gi < M) ? *(const float4*)(Ab + (long)gi*lda + k0 + scol)
                           : make_float4(0.f,0.f,0.f,0.f);
      *(float4*)&As[row*40 + scol] = va;
      int gj = j0 + row;
      float4 vb = (gj < N) ? *(const float4*)(Bb + (long)gj*ldb + k0 + scol)
                           : make_float4(0.f,0.f,0.f,0.f);
      *(float4*)&Bs[row*40 + scol] = vb;
    }
    __syncthreads();
    bf16x8 af[4], bfr[4];
#pragma unroll
    for (int mt = 0; mt < 4; mt++) af[mt]  = *(const bf16x8*)&As[(wm + mt*16 + col16)*40 + quad*8];
#pragma unroll
    for (int nt = 0; nt < 4; nt++) bfr[nt] = *(const bf16x8*)&Bs[(wn + nt*16 + col16)*40 + quad*8];
#pragma unroll
    for (int mt = 0; mt < 4; mt++)
#pragma unroll
      for (int nt = 0; nt < 4; nt++)
        acc[mt][nt] = __builtin_amdgcn_mfma_f32_16x16x32_bf16(af[mt], bfr[nt], acc[mt][nt], 0, 0, 0);
    __syncthreads();
  }
  if (MODE == 0){
    float* Cb = C + (long)hb*strideC;
#pragma unroll
    for (int mt = 0; mt < 4; mt++){
      int ibase = i0 + wm + mt*16 + quad*4;
#pragma unroll
      for (int nt = 0; nt < 4; nt++){
        int j = j0 + wn + nt*16 + col16;
        if (j < N){
#pragma unroll
          for (int rg = 0; rg < 4; rg++){
            int i = ibase + rg;
            if (i < M) Cb[(long)i*N + j] = acc[mt][nt][rg]*alpha;
          }
        }
      }
    }
  } else {
    int h = hb >> 2, b = hb & 3;
#pragma unroll
    for (int mt = 0; mt < 4; mt++){
      int ibase = i0 + wm + mt*16 + quad*4;
#pragma unroll
      for (int nt = 0; nt < 4; nt++){
        int n = j0 + wn + nt*16 + col16;
        if (n < NV){
          int d = n / 129, f = n - d*129;
          float* oc = C + ((long)(b*64 + h*16 + d)*Tt)*Ff + f;
#pragma unroll
          for (int rg = 0; rg < 4; rg++){
            int i = ibase + rg;
            if (i < M) oc[(long)i*Ff] = acc[mt][nt][rg];
          }
        }
      }
    }
  }
}

// softmax over row of 1000 f32; writes P bf16 (padded to 1024, zeros) in place
__global__ void k_softmax(float* __restrict__ S){
  float* row = S + (size_t)blockIdx.x * Tt;
  __hip_bfloat16* prow = (__hip_bfloat16*)row;
  int tid = threadIdx.x;
  __shared__ float red[4];
  float lv[4];
#pragma unroll
  for (int k = 0; k < 4; k++){ int idx = tid + k*256; lv[k] = (idx < Tt) ? row[idx] : -1e30f; }
  float m = fmaxf(fmaxf(lv[0], lv[1]), fmaxf(lv[2], lv[3]));
  m = blk_max256(m, red);
  float s = 0.f;
#pragma unroll
  for (int k = 0; k < 4; k++){ lv[k] = __expf(lv[k]-m); s += lv[k]; }
  s = blk_sum256(s, red);
  float inv = 1.f/s;
#pragma unroll
  for (int k = 0; k < 4; k++){
    int idx = tid + k*256;
    prow[idx] = __float2bfloat16(idx < Tt ? lv[k]*inv : 0.f);
  }
}

// ---------------- proj stage A: 1x1 conv 64->64 + bias + prelu, write to scratch,
// accumulate per-(b,t) sum/sumsq via segmented wave reduction + global atomics.
// Weights (16KB, fits K-cache) via wave-uniform global reads, input col in VGPRs.
__global__ __launch_bounds__(256) void k_projA(const float* __restrict__ in, float* __restrict__ out,
    const float* __restrict__ W, const float* __restrict__ bias,
    const float* __restrict__ pa, float* __restrict__ pstat){
  int gid = blockIdx.x*256 + threadIdx.x;
  float s1 = 0.f, s2 = 0.f;
  int r = 3999;
  if (gid < Bz*TF){
    int b = gid / TF;
    int p = gid - b*TF;
    r = gid / 129;        // = b*1000 + t  (since TF = 1000*129)
    size_t base = (size_t)b*CTF + p;
    float al = pa[0];
    float v[64];
#pragma unroll
    for (int c = 0; c < 64; c++) v[c] = in[base + (size_t)c*TF];
    for (int o = 0; o < 64; o++){
      float s = bias[o];
      const float4* w4 = (const float4*)&W[o*64];
#pragma unroll
      for (int c = 0; c < 16; c++){
        float4 w = w4[c];
        s += v[4*c]*w.x + v[4*c+1]*w.y + v[4*c+2]*w.z + v[4*c+3]*w.w;
      }
      s = s >= 0.f ? s : al*s;
      out[base + (size_t)o*TF] = s;
      s1 += s; s2 += s*s;
    }
  }
  // per-(b,t) row stats; a wave (64 consecutive gids) spans at most 2 rows of 129
  int rlo = __shfl(r, 0, 64), rhi = __shfl(r, 63, 64);
  if (rlo == rhi){
    float a1 = wave_sum(s1), a2 = wave_sum(s2);
    if ((threadIdx.x & 63) == 0){
      atomicAdd(&pstat[rlo*2], a1); atomicAdd(&pstat[rlo*2+1], a2);
    }
  } else {
    bool lo = (r == rlo);
    float a1 = wave_sum(lo ? s1 : 0.f);
    float a2 = wave_sum(lo ? s2 : 0.f);
    float b1 = wave_sum(lo ? 0.f : s1);
    float b2 = wave_sum(lo ? 0.f : s2);
    if ((threadIdx.x & 63) == 0){
      atomicAdd(&pstat[rlo*2], a1); atomicAdd(&pstat[rlo*2+1], a2);
      atomicAdd(&pstat[rhi*2], b1); atomicAdd(&pstat[rhi*2+1], b2);
    }
  }
}

// ---------------- proj stage B: LN over (c,f) per (b,t) + residual, final write ----
// Residual Y is the RAW conv output; GN+prelu applied inline (k_gnapply removed).
__global__ __launch_bounds__(256) void k_projB(const float* __restrict__ proj,
    const float* __restrict__ Y, float* __restrict__ Out,
    const float* __restrict__ pstat, const float* __restrict__ lng,
    const float* __restrict__ lnb,
    const float* __restrict__ gng, const float* __restrict__ gnb,
    const float* __restrict__ gna, const float* __restrict__ stat){
  int t = blockIdx.x, b = blockIdx.y;
  int r = b*1000 + t;
  const float n = 64.f*129.f;
  float mu = pstat[r*2] / n;
  float var = pstat[r*2+1] / n - mu*mu;
  float rstd = rsqrtf(var + EPSv);
  float gmu = stat[b*2] * (1.f/(float)CTF);
  float gvar = stat[b*2+1] * (1.f/(float)CTF) - gmu*gmu;
  float grs = rsqrtf(gvar + EPSv);
  float gal = gna[0];
  size_t base = (size_t)b*CTF + (size_t)t*Ff;
  for (int idx = threadIdx.x; idx < 64*Ff; idx += 256){
    int c = idx / Ff, f = idx - c*Ff;
    size_t off = base + (size_t)c*TF + f;
    float y = (Y[off] - gmu)*grs*gng[c] + gnb[c];
    y = y >= 0.f ? y : gal*y;
    Out[off] = (proj[off]-mu)*rstd*lng[idx] + lnb[idx] + y;
  }
}

extern "C" void kernel_launch(void* const* d_in, const int* in_sizes, int n_in,
                              void* d_out, int out_size, void* d_ws, size_t ws_size,
                              hipStream_t stream){
  const float* x       = (const float*)d_in[0];
  const float* br_g    = (const float*)d_in[1];
  const float* br_b    = (const float*)d_in[2];
  const float* lisa_w  = (const float*)d_in[3];
  const float* lisa_in = (const float*)d_in[4];
  const float* lisa_ll = (const float*)d_in[5];
  const float* lisa_lh = (const float*)d_in[6];
  const float* mix_g   = (const float*)d_in[7];
  const float* mix_b   = (const float*)d_in[8];
  const float* convb_w = (const float*)d_in[9];
  const float* convb_b = (const float*)d_in[10];
  const float* gn_g    = (const float*)d_in[11];
  const float* gn_b    = (const float*)d_in[12];
  const float* convb_a = (const float*)d_in[13];
  const float* q_w  = (const float*)d_in[14];
  const float* q_b  = (const float*)d_in[15];
  const float* q_a  = (const float*)d_in[16];
  const float* q_lg = (const float*)d_in[17];
  const float* q_lb = (const float*)d_in[18];
  const float* k_w  = (const float*)d_in[19];
  const float* k_b  = (const float*)d_in[20];
  const float* k_a  = (const float*)d_in[21];
  const float* k_lg = (const float*)d_in[22];
  const float* k_lb = (const float*)d_in[23];
  const float* v_w  = (const float*)d_in[24];
  const float* v_b  = (const float*)d_in[25];
  const float* v_a  = (const float*)d_in[26];
  const float* v_lg = (const float*)d_in[27];
  const float* v_lb = (const float*)d_in[28];
  const float* p_w  = (const float*)d_in[29];
  const float* p_b  = (const float*)d_in[30];
  const float* p_a  = (const float*)d_in[31];
  const float* p_lg = (const float*)d_in[32];
  const float* p_lb = (const float*)d_in[33];

  float* out  = (float*)d_out;
  float* buf0 = (float*)d_ws;          // bsum -> Z -> Vt|S -> proj scratch
  float* buf1 = buf0 + SZ;             // ln temp -> Y (raw conv output; GN applied inline)
  float* buf2 = buf1 + SZ;             // lisa_h temp -> Qm|Km|Vm (bf16)
  float* chm  = buf2 + SZ;             // 256
  float* filt = chm + 1536;            // 48 (pad 64)
  float* stat = filt + 64;             // 8  (pad 16)
  float* gapv = stat + 16;             // 33024 (lisa loop only)
  float* pstat = gapv;                 // 8000 -- ALIASES gapv (dead after lisa loop);
                                       // zeroed by k_zerop right before k_projA

  if (ws_size < (3*(size_t)SZ + 40000)*sizeof(float)) return;

  __hip_bfloat16* Qm = (__hip_bfloat16*)buf2;                 // 16*1000*544
  __hip_bfloat16* Km = Qm + (size_t)16*Tt*KQK;                // 16*1000*544
  __hip_bfloat16* Vm = Km + (size_t)16*Tt*KQK;                // 16*1000*2064
  __hip_bfloat16* Z  = (__hip_bfloat16*)buf0;                 // 4*96*129000 bf16 (99 MB)
  ushort* Vt = (ushort*)buf0;                                 // 16*2064*1024 bf16 (after Z dead)
  float*  S  = buf0 + (size_t)16*NV*KPV/2;                    // 16*1000*1000 f32

  k_zero8<<<1, 64, 0, stream>>>(stat);

  const int dils[3] = {3, 5, 7};
  for (int i = 0; i < 3; i++){
    k_ln4d<<<2016, 256, 0, stream>>>(x, buf1, br_g + i*64, br_b + i*64);
    k_chmean<<<256, 256, 0, stream>>>(buf1, chm);
    k_filt<<<1, 64, 0, stream>>>(chm, lisa_w + i*768, filt);
    k_lisa_h<<<Bz*Cc*Tt, 64, 0, stream>>>(buf1, buf2, filt, lisa_in + i*64, lisa_ll + i*64, lisa_lh + i*64, dils[i]);
    k_ln4d<<<2016, 256, 0, stream>>>(buf2, buf1, br_g + (i+3)*64, br_b + (i+3)*64);
    // vertical-stage channel mean derived from gapv (saves a 132MB chmean pass):
    // chm[b,c] = (1/Ff) * sum_f gapv  since gapv is already the t-mean
    k_colmean<<<dim3(3, 64, 4), 256, 0, stream>>>(buf1, gapv);
    k_chmg<<<256, 64, 0, stream>>>(gapv, chm);
    k_filt<<<1, 64, 0, stream>>>(chm, lisa_w + (i+3)*768, filt);
    k_lisa_v<<<dim3(30, 64, 4), 256, 0, stream>>>(buf1, x, buf0, filt, gapv,
        lisa_in + (i+3)*64, lisa_ll + (i+3)*64, lisa_lh + (i+3)*64,
        mix_g + i*64, mix_b + i*64, dils[i], i > 0 ? 1 : 0);
  }
  k_convb<<<2016, 256, 0, stream>>>(buf0, buf1, convb_w, convb_b, stat);
  // NOTE: no k_gnapply -- GN+prelu fused into k_qkvP and k_projB
  k_qkvP<<<2016, 256, 0, stream>>>(buf1, gn_g, gn_b, convb_a, stat,
      q_w, q_b, q_a, k_w, k_b, k_a, v_w, v_b, v_a, Z);
  k_qkvN<<<dim3(1000, 4), 256, 0, stream>>>(Z, q_lg, q_lb, k_lg, k_lb, v_lg, v_lb, Qm, Km, Vm);
  k_vt<<<dim3(16, 33, 16), 256, 0, stream>>>((const ushort*)Vm, Vt);
  k_gemm<0><<<dim3(8, 8, 16), 256, 0, stream>>>(
      (const ushort*)Qm, KQK, (long)Tt*KQK,
      (const ushort*)Km, KQK, (long)Tt*KQK,
      S, (long)Tt*Tt, Tt, Tt, KQK, 0.04402254531f);
  k_softmax<<<16000, 256, 0, stream>>>(S);
  k_gemm<1><<<dim3(17, 8, 16), 256, 0, stream>>>(
      (const ushort*)S, LDP, (long)Tt*LDP,
      Vt, KPV, (long)NV*KPV,
      out, 0, Tt, NV, KPV, 1.f);
  // proj: conv+prelu+stats into buf0 (free after attention), then LN+residual into out
  k_zerop<<<32, 256, 0, stream>>>(pstat);
  k_projA<<<2016, 256, 0, stream>>>(out, buf0, p_w, p_b, p_a, pstat);
  k_projB<<<dim3(1000, 4), 256, 0, stream>>>(buf0, buf1, out, pstat, p_lg, p_lb,
      gn_g, gn_b, convb_a, stat);
}